// Round 1
// baseline (1871.400 us; speedup 1.0000x reference)
//
#include <hip/hip_runtime.h>
#include <hip/hip_bf16.h>

#define N_NODES 100000
#define N_EDGES 1600000
#define FEAT 64
#define NGRAPH 256

// ---------------- CSR build ----------------

__global__ void k_hist(const int* __restrict__ dst, int* __restrict__ deg) {
    int e = blockIdx.x * blockDim.x + threadIdx.x;
    if (e < N_EDGES) atomicAdd(&deg[dst[e]], 1);
}

// Single-block exclusive scan over N_NODES degrees (in place), also copies
// the start offsets into cursor[].
__global__ __launch_bounds__(1024) void k_scan(int* __restrict__ deg_off,
                                               int* __restrict__ cursor) {
    __shared__ int partial[1024];
    const int CH = (N_NODES + 1023) / 1024;  // 98
    int t = threadIdx.x;
    int begin = t * CH;
    int end = begin + CH; if (end > N_NODES) end = N_NODES;
    int sum = 0;
    for (int i = begin; i < end; ++i) sum += deg_off[i];
    partial[t] = sum;
    __syncthreads();
    // Hillis-Steele inclusive scan
    for (int off = 1; off < 1024; off <<= 1) {
        int v = partial[t];
        int add = (t >= off) ? partial[t - off] : 0;
        __syncthreads();
        partial[t] = v + add;
        __syncthreads();
    }
    int prefix = (t == 0) ? 0 : partial[t - 1];
    for (int i = begin; i < end; ++i) {
        int d = deg_off[i];
        deg_off[i] = prefix;   // start offset
        cursor[i]  = prefix;   // scatter cursor
        prefix += d;
    }
}

__global__ void k_scatter(const int* __restrict__ src, const int* __restrict__ dst,
                          int* __restrict__ cursor, int* __restrict__ ssrc) {
    int e = blockIdx.x * blockDim.x + threadIdx.x;
    if (e < N_EDGES) {
        int pos = atomicAdd(&cursor[dst[e]], 1);
        ssrc[pos] = src[e];
    }
}

// ---------------- GIN aggregation: agg[i] = h[i] + sum_{j in N(i)} h[src_j] ----------------
// wave per node; lane = feature. offsets[i] = start, cursor[i] = end (post-scatter).

__global__ __launch_bounds__(256) void k_aggregate(const float* __restrict__ hin,
                                                   float* __restrict__ agg,
                                                   const int* __restrict__ offs,
                                                   const int* __restrict__ ends,
                                                   const int* __restrict__ ssrc) {
    int node = blockIdx.x * 4 + (threadIdx.x >> 6);
    int lane = threadIdx.x & 63;
    if (node >= N_NODES) return;
    float v = hin[node * FEAT + lane];
    int s = offs[node], e = ends[node];
    int j = s;
    for (; j + 1 < e; j += 2) {
        int s0 = ssrc[j], s1 = ssrc[j + 1];
        float a0 = hin[s0 * FEAT + lane];
        float a1 = hin[s1 * FEAT + lane];
        v += a0;
        v += a1;
    }
    if (j < e) v += hin[ssrc[j] * FEAT + lane];
    agg[node * FEAT + lane] = v;
}

// ---------------- fused 64->64->64 MLP (+optional output relu) ----------------
// wave per node, weights staged in LDS, __shfl broadcast of activations.

template <bool RELU_OUT>
__global__ __launch_bounds__(256) void k_mlp(const float* __restrict__ agg,
                                             float* __restrict__ hout,
                                             const float* __restrict__ W1,
                                             const float* __restrict__ b1,
                                             const float* __restrict__ W2,
                                             const float* __restrict__ b2) {
    __shared__ float w1s[FEAT * FEAT];
    __shared__ float w2s[FEAT * FEAT];
    __shared__ float b1s[FEAT];
    __shared__ float b2s[FEAT];
    for (int i = threadIdx.x; i < FEAT * FEAT; i += 256) {
        w1s[i] = W1[i];
        w2s[i] = W2[i];
    }
    if (threadIdx.x < FEAT) {
        b1s[threadIdx.x] = b1[threadIdx.x];
        b2s[threadIdx.x] = b2[threadIdx.x];
    }
    __syncthreads();

    int lane = threadIdx.x & 63;
    int wid  = threadIdx.x >> 6;
    int wavesTotal = gridDim.x * 4;
    for (int node = blockIdx.x * 4 + wid; node < N_NODES; node += wavesTotal) {
        float a = agg[node * FEAT + lane];
        float h = b1s[lane];
#pragma unroll
        for (int k = 0; k < FEAT; ++k)
            h = fmaf(__shfl(a, k), w1s[k * FEAT + lane], h);
        h = fmaxf(h, 0.0f);
        float o = b2s[lane];
#pragma unroll
        for (int k = 0; k < FEAT; ++k)
            o = fmaf(__shfl(h, k), w2s[k * FEAT + lane], o);
        if (RELU_OUT) o = fmaxf(o, 0.0f);
        hout[node * FEAT + lane] = o;
    }
}

// ---------------- last layer (64->1->1) fused with mean-pool accumulation ----------------

__global__ __launch_bounds__(256) void k_last(const float* __restrict__ agg,
                                              const int* __restrict__ batch,
                                              const float* __restrict__ W1l,
                                              const float* __restrict__ b1l,
                                              const float* __restrict__ W2l,
                                              const float* __restrict__ b2l,
                                              float* __restrict__ sums,
                                              float* __restrict__ counts) {
    int node = blockIdx.x * 4 + (threadIdx.x >> 6);
    int lane = threadIdx.x & 63;
    if (node >= N_NODES) return;
    float v = agg[node * FEAT + lane] * W1l[lane];
#pragma unroll
    for (int off = 32; off; off >>= 1) v += __shfl_xor(v, off);
    if (lane == 0) {
        float h = fmaxf(v + b1l[0], 0.0f);
        float o = fmaf(h, W2l[0], b2l[0]);
        int g = batch[node];
        atomicAdd(&sums[g], o);
        atomicAdd(&counts[g], 1.0f);
    }
}

__global__ void k_final(const float* __restrict__ sums, const float* __restrict__ counts,
                        float* __restrict__ out) {
    int g = blockIdx.x * blockDim.x + threadIdx.x;
    if (g < NGRAPH) out[g] = sums[g] / fmaxf(counts[g], 1.0f);
}

// ---------------- launch ----------------

extern "C" void kernel_launch(void* const* d_in, const int* in_sizes, int n_in,
                              void* d_out, int out_size, void* d_ws, size_t ws_size,
                              hipStream_t stream) {
    const float* x    = (const float*)d_in[0];
    const int*   ei   = (const int*)d_in[1];   // [2][N_EDGES]
    const int*   bat  = (const int*)d_in[2];
    const float* W1   = (const float*)d_in[3]; // [4][64][64]
    const float* b1   = (const float*)d_in[4]; // [4][64]
    const float* W2   = (const float*)d_in[5];
    const float* b2   = (const float*)d_in[6];
    const float* W1l  = (const float*)d_in[7];
    const float* b1l  = (const float*)d_in[8];
    const float* W2l  = (const float*)d_in[9];
    const float* b2l  = (const float*)d_in[10];
    float* out = (float*)d_out;

    const int* srcI = ei;            // row 0
    const int* dstI = ei + N_EDGES;  // row 1

    // workspace carve-up
    char* ws = (char*)d_ws;
    float* agg   = (float*)ws;                              ws += (size_t)N_NODES * FEAT * 4;
    float* h     = (float*)ws;                              ws += (size_t)N_NODES * FEAT * 4;
    int*   offs  = (int*)ws;                                ws += (size_t)N_NODES * 4;
    int*   curs  = (int*)ws;                                ws += (size_t)N_NODES * 4;
    int*   ssrc  = (int*)ws;                                ws += (size_t)N_EDGES * 4;
    float* sums  = (float*)ws;                              ws += NGRAPH * 4;
    float* cnts  = (float*)ws;                              ws += NGRAPH * 4;

    // zero degree array and pool accumulators
    hipMemsetAsync(offs, 0, (size_t)N_NODES * 4, stream);
    hipMemsetAsync(sums, 0, (size_t)NGRAPH * 2 * 4, stream);  // sums + cnts contiguous

    const int EB = 256;
    const int egrid = (N_EDGES + EB - 1) / EB;
    k_hist<<<egrid, EB, 0, stream>>>(dstI, offs);
    k_scan<<<1, 1024, 0, stream>>>(offs, curs);
    k_scatter<<<egrid, EB, 0, stream>>>(srcI, dstI, curs, ssrc);

    const int ngrid = (N_NODES + 3) / 4;  // 4 nodes (waves) per 256-thread block
    const int mlpgrid = 1024;

    // layers 0..3
    for (int l = 0; l < 4; ++l) {
        const float* hin = (l == 0) ? x : h;
        k_aggregate<<<ngrid, 256, 0, stream>>>(hin, agg, offs, curs, ssrc);
        k_mlp<true><<<mlpgrid, 256, 0, stream>>>(agg, h,
                                                 W1 + (size_t)l * FEAT * FEAT,
                                                 b1 + (size_t)l * FEAT,
                                                 W2 + (size_t)l * FEAT * FEAT,
                                                 b2 + (size_t)l * FEAT);
    }
    // last layer + pool
    k_aggregate<<<ngrid, 256, 0, stream>>>(h, agg, offs, curs, ssrc);
    k_last<<<ngrid, 256, 0, stream>>>(agg, bat, W1l, b1l, W2l, b2l, sums, cnts);
    k_final<<<1, NGRAPH, 0, stream>>>(sums, cnts, out);
}

// Round 2
// 1443.859 us; speedup vs baseline: 1.2961x; 1.2961x over previous
//
#include <hip/hip_runtime.h>
#include <hip/hip_bf16.h>

#define N_NODES 100000
#define N_EDGES 1600000
#define FEAT 64
#define NGRAPH 256

// ---------------- CSR build ----------------

__global__ void k_hist(const int* __restrict__ dst, int* __restrict__ deg) {
    int e = blockIdx.x * blockDim.x + threadIdx.x;
    if (e < N_EDGES) atomicAdd(&deg[dst[e]], 1);
}

// Single-block exclusive scan over N_NODES degrees (in place), also copies
// the start offsets into cursor[].
__global__ __launch_bounds__(1024) void k_scan(int* __restrict__ deg_off,
                                               int* __restrict__ cursor) {
    __shared__ int partial[1024];
    const int CH = (N_NODES + 1023) / 1024;  // 98
    int t = threadIdx.x;
    int begin = t * CH;
    int end = begin + CH; if (end > N_NODES) end = N_NODES;
    int sum = 0;
    for (int i = begin; i < end; ++i) sum += deg_off[i];
    partial[t] = sum;
    __syncthreads();
    // Hillis-Steele inclusive scan
    for (int off = 1; off < 1024; off <<= 1) {
        int v = partial[t];
        int add = (t >= off) ? partial[t - off] : 0;
        __syncthreads();
        partial[t] = v + add;
        __syncthreads();
    }
    int prefix = (t == 0) ? 0 : partial[t - 1];
    for (int i = begin; i < end; ++i) {
        int d = deg_off[i];
        deg_off[i] = prefix;   // start offset
        cursor[i]  = prefix;   // scatter cursor
        prefix += d;
    }
}

__global__ void k_scatter(const int* __restrict__ src, const int* __restrict__ dst,
                          int* __restrict__ cursor, int* __restrict__ ssrc) {
    int e = blockIdx.x * blockDim.x + threadIdx.x;
    if (e < N_EDGES) {
        int pos = atomicAdd(&cursor[dst[e]], 1);
        ssrc[pos] = src[e];
    }
}

// ---------------- GIN aggregation: agg[i] = h[i] + sum_{j in N(i)} h[src_j] ----------------
// wave per node; lane = feature. offsets[i] = start, cursor[i] = end (post-scatter).

__global__ __launch_bounds__(256) void k_aggregate(const float* __restrict__ hin,
                                                   float* __restrict__ agg,
                                                   const int* __restrict__ offs,
                                                   const int* __restrict__ ends,
                                                   const int* __restrict__ ssrc) {
    int node = blockIdx.x * 4 + (threadIdx.x >> 6);
    int lane = threadIdx.x & 63;
    if (node >= N_NODES) return;
    float v = hin[node * FEAT + lane];
    int s = offs[node], e = ends[node];
    int j = s;
    for (; j + 1 < e; j += 2) {
        int s0 = ssrc[j], s1 = ssrc[j + 1];
        float a0 = hin[s0 * FEAT + lane];
        float a1 = hin[s1 * FEAT + lane];
        v += a0;
        v += a1;
    }
    if (j < e) v += hin[ssrc[j] * FEAT + lane];
    agg[node * FEAT + lane] = v;
}

// ---------------- fused 64->64->64 MLP (+output relu) ----------------
// wave per node, weights staged in LDS, __shfl broadcast of activations.

template <bool RELU_OUT>
__global__ __launch_bounds__(256) void k_mlp(const float* __restrict__ agg,
                                             float* __restrict__ hout,
                                             const float* __restrict__ W1,
                                             const float* __restrict__ b1,
                                             const float* __restrict__ W2,
                                             const float* __restrict__ b2) {
    __shared__ float w1s[FEAT * FEAT];
    __shared__ float w2s[FEAT * FEAT];
    __shared__ float b1s[FEAT];
    __shared__ float b2s[FEAT];
    for (int i = threadIdx.x; i < FEAT * FEAT; i += 256) {
        w1s[i] = W1[i];
        w2s[i] = W2[i];
    }
    if (threadIdx.x < FEAT) {
        b1s[threadIdx.x] = b1[threadIdx.x];
        b2s[threadIdx.x] = b2[threadIdx.x];
    }
    __syncthreads();

    int lane = threadIdx.x & 63;
    int wid  = threadIdx.x >> 6;
    int wavesTotal = gridDim.x * 4;
    for (int node = blockIdx.x * 4 + wid; node < N_NODES; node += wavesTotal) {
        float a = agg[node * FEAT + lane];
        float h = b1s[lane];
#pragma unroll
        for (int k = 0; k < FEAT; ++k)
            h = fmaf(__shfl(a, k), w1s[k * FEAT + lane], h);
        h = fmaxf(h, 0.0f);
        float o = b2s[lane];
#pragma unroll
        for (int k = 0; k < FEAT; ++k)
            o = fmaf(__shfl(h, k), w2s[k * FEAT + lane], o);
        if (RELU_OUT) o = fmaxf(o, 0.0f);
        hout[node * FEAT + lane] = o;
    }
}

// ---------------- last layer: fused aggregate + (64->1->1) MLP -> scalar per node ----------------
// No atomics: writes o[node]; pooling done by k_pool via sorted batch.

__global__ __launch_bounds__(256) void k_lastagg(const float* __restrict__ hin,
                                                 const int* __restrict__ offs,
                                                 const int* __restrict__ ends,
                                                 const int* __restrict__ ssrc,
                                                 const float* __restrict__ W1l,
                                                 const float* __restrict__ b1l,
                                                 const float* __restrict__ W2l,
                                                 const float* __restrict__ b2l,
                                                 float* __restrict__ o) {
    int node = blockIdx.x * 4 + (threadIdx.x >> 6);
    int lane = threadIdx.x & 63;
    if (node >= N_NODES) return;
    float v = hin[node * FEAT + lane];
    int s = offs[node], e = ends[node];
    int j = s;
    for (; j + 1 < e; j += 2) {
        int s0 = ssrc[j], s1 = ssrc[j + 1];
        v += hin[s0 * FEAT + lane];
        v += hin[s1 * FEAT + lane];
    }
    if (j < e) v += hin[ssrc[j] * FEAT + lane];
    v *= W1l[lane];
#pragma unroll
    for (int off = 32; off; off >>= 1) v += __shfl_xor(v, off);
    if (lane == 0) {
        float h1 = fmaxf(v + b1l[0], 0.0f);
        o[node] = fmaf(h1, W2l[0], b2l[0]);
    }
}

// ---------------- mean pool: one block per graph, sorted batch, binary search ----------------

__global__ __launch_bounds__(256) void k_pool(const float* __restrict__ o,
                                              const int* __restrict__ batch,
                                              float* __restrict__ out) {
    int g = blockIdx.x;
    // lower_bound(batch, g)
    int lo = 0, hi = N_NODES;
    while (lo < hi) { int mid = (lo + hi) >> 1; if (batch[mid] < g) lo = mid + 1; else hi = mid; }
    int start = lo;
    // lower_bound(batch, g+1), continuing from start
    hi = N_NODES;
    while (lo < hi) { int mid = (lo + hi) >> 1; if (batch[mid] < g + 1) lo = mid + 1; else hi = mid; }
    int end = lo;

    float s = 0.0f;
    for (int i = start + threadIdx.x; i < end; i += 256) s += o[i];
#pragma unroll
    for (int off = 32; off; off >>= 1) s += __shfl_xor(s, off);
    __shared__ float red[4];
    int lane = threadIdx.x & 63, wid = threadIdx.x >> 6;
    if (lane == 0) red[wid] = s;
    __syncthreads();
    if (threadIdx.x == 0) {
        float t = red[0] + red[1] + red[2] + red[3];
        float c = (float)(end - start);
        out[g] = t / fmaxf(c, 1.0f);
    }
}

// ---------------- launch ----------------

extern "C" void kernel_launch(void* const* d_in, const int* in_sizes, int n_in,
                              void* d_out, int out_size, void* d_ws, size_t ws_size,
                              hipStream_t stream) {
    const float* x    = (const float*)d_in[0];
    const int*   ei   = (const int*)d_in[1];   // [2][N_EDGES]
    const int*   bat  = (const int*)d_in[2];
    const float* W1   = (const float*)d_in[3]; // [4][64][64]
    const float* b1   = (const float*)d_in[4]; // [4][64]
    const float* W2   = (const float*)d_in[5];
    const float* b2   = (const float*)d_in[6];
    const float* W1l  = (const float*)d_in[7];
    const float* b1l  = (const float*)d_in[8];
    const float* W2l  = (const float*)d_in[9];
    const float* b2l  = (const float*)d_in[10];
    float* out = (float*)d_out;

    const int* srcI = ei;            // row 0
    const int* dstI = ei + N_EDGES;  // row 1

    // workspace carve-up
    char* ws = (char*)d_ws;
    float* agg   = (float*)ws;                              ws += (size_t)N_NODES * FEAT * 4;
    float* h     = (float*)ws;                              ws += (size_t)N_NODES * FEAT * 4;
    int*   offs  = (int*)ws;                                ws += (size_t)N_NODES * 4;
    int*   curs  = (int*)ws;                                ws += (size_t)N_NODES * 4;
    int*   ssrc  = (int*)ws;                                ws += (size_t)N_EDGES * 4;
    float* onode = (float*)ws;                              ws += (size_t)N_NODES * 4;

    // zero degree array
    hipMemsetAsync(offs, 0, (size_t)N_NODES * 4, stream);

    const int EB = 256;
    const int egrid = (N_EDGES + EB - 1) / EB;
    k_hist<<<egrid, EB, 0, stream>>>(dstI, offs);
    k_scan<<<1, 1024, 0, stream>>>(offs, curs);
    k_scatter<<<egrid, EB, 0, stream>>>(srcI, dstI, curs, ssrc);

    const int ngrid = (N_NODES + 3) / 4;  // 4 nodes (waves) per 256-thread block
    const int mlpgrid = 1024;

    // layers 0..3
    for (int l = 0; l < 4; ++l) {
        const float* hin = (l == 0) ? x : h;
        k_aggregate<<<ngrid, 256, 0, stream>>>(hin, agg, offs, curs, ssrc);
        k_mlp<true><<<mlpgrid, 256, 0, stream>>>(agg, h,
                                                 W1 + (size_t)l * FEAT * FEAT,
                                                 b1 + (size_t)l * FEAT,
                                                 W2 + (size_t)l * FEAT * FEAT,
                                                 b2 + (size_t)l * FEAT);
    }
    // last layer: fused aggregate + 64->1->1, then pool
    k_lastagg<<<ngrid, 256, 0, stream>>>(h, offs, curs, ssrc, W1l, b1l, W2l, b2l, onode);
    k_pool<<<NGRAPH, 256, 0, stream>>>(onode, bat, out);
}

// Round 3
// 1230.616 us; speedup vs baseline: 1.5207x; 1.1733x over previous
//
#include <hip/hip_runtime.h>
#include <hip/hip_bf16.h>

#define N_NODES 100000
#define N_EDGES 1600000
#define FEAT 64
#define NGRAPH 256

#define SCAN_CHUNK 1024
#define SCAN_BLOCKS ((N_NODES + SCAN_CHUNK - 1) / SCAN_CHUNK)  // 98

// ---------------- CSR build ----------------

__global__ void k_hist(const int* __restrict__ dst, int* __restrict__ deg) {
    int e = blockIdx.x * blockDim.x + threadIdx.x;
    if (e < N_EDGES) atomicAdd(&deg[dst[e]], 1);
}

// Phase 1: per-block sums of 1024-element chunks.
__global__ __launch_bounds__(256) void k_scan1(const int* __restrict__ deg,
                                               int* __restrict__ bsum) {
    int t = threadIdx.x;
    int base = blockIdx.x * SCAN_CHUNK + t * 4;
    int4 d = make_int4(0, 0, 0, 0);
    if (base + 3 < N_NODES) {
        d = *reinterpret_cast<const int4*>(&deg[base]);
    } else {
        if (base + 0 < N_NODES) d.x = deg[base + 0];
        if (base + 1 < N_NODES) d.y = deg[base + 1];
        if (base + 2 < N_NODES) d.z = deg[base + 2];
    }
    int v = d.x + d.y + d.z + d.w;
#pragma unroll
    for (int off = 32; off; off >>= 1) v += __shfl_xor(v, off);
    __shared__ int red[4];
    int lane = t & 63, wid = t >> 6;
    if (lane == 0) red[wid] = v;
    __syncthreads();
    if (t == 0) bsum[blockIdx.x] = red[0] + red[1] + red[2] + red[3];
}

// Phase 2: exclusive scan of the 98 block sums (single tiny block).
__global__ __launch_bounds__(128) void k_scan2(int* __restrict__ bsum) {
    __shared__ int s[128];
    int t = threadIdx.x;
    int v = (t < SCAN_BLOCKS) ? bsum[t] : 0;
    s[t] = v;
    __syncthreads();
    for (int off = 1; off < 128; off <<= 1) {
        int add = (t >= off) ? s[t - off] : 0;
        __syncthreads();
        s[t] += add;
        __syncthreads();
    }
    if (t < SCAN_BLOCKS) bsum[t] = (t ? s[t - 1] : 0);
}

// Phase 3: block-local exclusive scan + block prefix -> offs, curs (in place over deg==offs).
__global__ __launch_bounds__(256) void k_scan3(int* __restrict__ deg_off,
                                               int* __restrict__ cursor,
                                               const int* __restrict__ bsum) {
    int t = threadIdx.x;
    int base = blockIdx.x * SCAN_CHUNK + t * 4;
    int4 d = make_int4(0, 0, 0, 0);
    bool full = (base + 3 < N_NODES);
    if (full) {
        d = *reinterpret_cast<const int4*>(&deg_off[base]);
    } else {
        if (base + 0 < N_NODES) d.x = deg_off[base + 0];
        if (base + 1 < N_NODES) d.y = deg_off[base + 1];
        if (base + 2 < N_NODES) d.z = deg_off[base + 2];
    }
    int total = d.x + d.y + d.z + d.w;
    __shared__ int sc[256];
    sc[t] = total;
    __syncthreads();
    for (int off = 1; off < 256; off <<= 1) {
        int add = (t >= off) ? sc[t - off] : 0;
        __syncthreads();
        sc[t] += add;
        __syncthreads();
    }
    int texc = (t ? sc[t - 1] : 0) + bsum[blockIdx.x];
    int4 o;
    o.x = texc;
    o.y = o.x + d.x;
    o.z = o.y + d.y;
    o.w = o.z + d.z;
    if (full) {
        *reinterpret_cast<int4*>(&deg_off[base]) = o;
        *reinterpret_cast<int4*>(&cursor[base]) = o;
    } else {
        if (base + 0 < N_NODES) { deg_off[base + 0] = o.x; cursor[base + 0] = o.x; }
        if (base + 1 < N_NODES) { deg_off[base + 1] = o.y; cursor[base + 1] = o.y; }
        if (base + 2 < N_NODES) { deg_off[base + 2] = o.z; cursor[base + 2] = o.z; }
    }
}

__global__ void k_scatter(const int* __restrict__ src, const int* __restrict__ dst,
                          int* __restrict__ cursor, int* __restrict__ ssrc) {
    int e = blockIdx.x * blockDim.x + threadIdx.x;
    if (e < N_EDGES) {
        int pos = atomicAdd(&cursor[dst[e]], 1);
        ssrc[pos] = src[e];
    }
}

// ---------------- GIN aggregation: agg[i] = h[i] + sum_{j in N(i)} h[src_j] ----------------
// wave per node; lane = feature.

__global__ __launch_bounds__(256) void k_aggregate(const float* __restrict__ hin,
                                                   float* __restrict__ agg,
                                                   const int* __restrict__ offs,
                                                   const int* __restrict__ ends,
                                                   const int* __restrict__ ssrc) {
    int node = blockIdx.x * 4 + (threadIdx.x >> 6);
    int lane = threadIdx.x & 63;
    if (node >= N_NODES) return;
    float v = hin[node * FEAT + lane];
    int s = offs[node], e = ends[node];
    int j = s;
    for (; j + 1 < e; j += 2) {
        int s0 = ssrc[j], s1 = ssrc[j + 1];
        float a0 = hin[s0 * FEAT + lane];
        float a1 = hin[s1 * FEAT + lane];
        v += a0;
        v += a1;
    }
    if (j < e) v += hin[ssrc[j] * FEAT + lane];
    agg[node * FEAT + lane] = v;
}

// ---------------- fused 64->64->64 MLP (+output relu) ----------------

template <bool RELU_OUT>
__global__ __launch_bounds__(256) void k_mlp(const float* __restrict__ agg,
                                             float* __restrict__ hout,
                                             const float* __restrict__ W1,
                                             const float* __restrict__ b1,
                                             const float* __restrict__ W2,
                                             const float* __restrict__ b2) {
    __shared__ float w1s[FEAT * FEAT];
    __shared__ float w2s[FEAT * FEAT];
    __shared__ float b1s[FEAT];
    __shared__ float b2s[FEAT];
    for (int i = threadIdx.x; i < FEAT * FEAT; i += 256) {
        w1s[i] = W1[i];
        w2s[i] = W2[i];
    }
    if (threadIdx.x < FEAT) {
        b1s[threadIdx.x] = b1[threadIdx.x];
        b2s[threadIdx.x] = b2[threadIdx.x];
    }
    __syncthreads();

    int lane = threadIdx.x & 63;
    int wid  = threadIdx.x >> 6;
    int wavesTotal = gridDim.x * 4;
    for (int node = blockIdx.x * 4 + wid; node < N_NODES; node += wavesTotal) {
        float a = agg[node * FEAT + lane];
        float h = b1s[lane];
#pragma unroll
        for (int k = 0; k < FEAT; ++k)
            h = fmaf(__shfl(a, k), w1s[k * FEAT + lane], h);
        h = fmaxf(h, 0.0f);
        float o = b2s[lane];
#pragma unroll
        for (int k = 0; k < FEAT; ++k)
            o = fmaf(__shfl(h, k), w2s[k * FEAT + lane], o);
        if (RELU_OUT) o = fmaxf(o, 0.0f);
        hout[node * FEAT + lane] = o;
    }
}

// ---------------- last layer: fused aggregate + (64->1->1) MLP -> scalar per node ----------------

__global__ __launch_bounds__(256) void k_lastagg(const float* __restrict__ hin,
                                                 const int* __restrict__ offs,
                                                 const int* __restrict__ ends,
                                                 const int* __restrict__ ssrc,
                                                 const float* __restrict__ W1l,
                                                 const float* __restrict__ b1l,
                                                 const float* __restrict__ W2l,
                                                 const float* __restrict__ b2l,
                                                 float* __restrict__ o) {
    int node = blockIdx.x * 4 + (threadIdx.x >> 6);
    int lane = threadIdx.x & 63;
    if (node >= N_NODES) return;
    float v = hin[node * FEAT + lane];
    int s = offs[node], e = ends[node];
    int j = s;
    for (; j + 1 < e; j += 2) {
        int s0 = ssrc[j], s1 = ssrc[j + 1];
        v += hin[s0 * FEAT + lane];
        v += hin[s1 * FEAT + lane];
    }
    if (j < e) v += hin[ssrc[j] * FEAT + lane];
    v *= W1l[lane];
#pragma unroll
    for (int off = 32; off; off >>= 1) v += __shfl_xor(v, off);
    if (lane == 0) {
        float h1 = fmaxf(v + b1l[0], 0.0f);
        o[node] = fmaf(h1, W2l[0], b2l[0]);
    }
}

// ---------------- mean pool: one block per graph, sorted batch, binary search ----------------

__global__ __launch_bounds__(256) void k_pool(const float* __restrict__ o,
                                              const int* __restrict__ batch,
                                              float* __restrict__ out) {
    int g = blockIdx.x;
    int lo = 0, hi = N_NODES;
    while (lo < hi) { int mid = (lo + hi) >> 1; if (batch[mid] < g) lo = mid + 1; else hi = mid; }
    int start = lo;
    hi = N_NODES;
    while (lo < hi) { int mid = (lo + hi) >> 1; if (batch[mid] < g + 1) lo = mid + 1; else hi = mid; }
    int end = lo;

    float s = 0.0f;
    for (int i = start + threadIdx.x; i < end; i += 256) s += o[i];
#pragma unroll
    for (int off = 32; off; off >>= 1) s += __shfl_xor(s, off);
    __shared__ float red[4];
    int lane = threadIdx.x & 63, wid = threadIdx.x >> 6;
    if (lane == 0) red[wid] = s;
    __syncthreads();
    if (threadIdx.x == 0) {
        float t = red[0] + red[1] + red[2] + red[3];
        float c = (float)(end - start);
        out[g] = t / fmaxf(c, 1.0f);
    }
}

// ---------------- launch ----------------

extern "C" void kernel_launch(void* const* d_in, const int* in_sizes, int n_in,
                              void* d_out, int out_size, void* d_ws, size_t ws_size,
                              hipStream_t stream) {
    const float* x    = (const float*)d_in[0];
    const int*   ei   = (const int*)d_in[1];   // [2][N_EDGES]
    const int*   bat  = (const int*)d_in[2];
    const float* W1   = (const float*)d_in[3]; // [4][64][64]
    const float* b1   = (const float*)d_in[4]; // [4][64]
    const float* W2   = (const float*)d_in[5];
    const float* b2   = (const float*)d_in[6];
    const float* W1l  = (const float*)d_in[7];
    const float* b1l  = (const float*)d_in[8];
    const float* W2l  = (const float*)d_in[9];
    const float* b2l  = (const float*)d_in[10];
    float* out = (float*)d_out;

    const int* srcI = ei;            // row 0
    const int* dstI = ei + N_EDGES;  // row 1

    // workspace carve-up (all 16B-aligned)
    char* ws = (char*)d_ws;
    float* agg   = (float*)ws;                              ws += (size_t)N_NODES * FEAT * 4;
    float* h     = (float*)ws;                              ws += (size_t)N_NODES * FEAT * 4;
    int*   offs  = (int*)ws;                                ws += (size_t)N_NODES * 4;
    int*   curs  = (int*)ws;                                ws += (size_t)N_NODES * 4;
    int*   ssrc  = (int*)ws;                                ws += (size_t)N_EDGES * 4;
    float* onode = (float*)ws;                              ws += (size_t)N_NODES * 4;
    int*   bsum  = (int*)ws;                                ws += 128 * 4;

    hipMemsetAsync(offs, 0, (size_t)N_NODES * 4, stream);

    const int EB = 256;
    const int egrid = (N_EDGES + EB - 1) / EB;
    k_hist<<<egrid, EB, 0, stream>>>(dstI, offs);
    k_scan1<<<SCAN_BLOCKS, 256, 0, stream>>>(offs, bsum);
    k_scan2<<<1, 128, 0, stream>>>(bsum);
    k_scan3<<<SCAN_BLOCKS, 256, 0, stream>>>(offs, curs, bsum);
    k_scatter<<<egrid, EB, 0, stream>>>(srcI, dstI, curs, ssrc);

    const int ngrid = (N_NODES + 3) / 4;  // 4 nodes (waves) per 256-thread block
    const int mlpgrid = 1024;

    // layers 0..3
    for (int l = 0; l < 4; ++l) {
        const float* hin = (l == 0) ? x : h;
        k_aggregate<<<ngrid, 256, 0, stream>>>(hin, agg, offs, curs, ssrc);
        k_mlp<true><<<mlpgrid, 256, 0, stream>>>(agg, h,
                                                 W1 + (size_t)l * FEAT * FEAT,
                                                 b1 + (size_t)l * FEAT,
                                                 W2 + (size_t)l * FEAT * FEAT,
                                                 b2 + (size_t)l * FEAT);
    }
    // last layer: fused aggregate + 64->1->1, then pool
    k_lastagg<<<ngrid, 256, 0, stream>>>(h, offs, curs, ssrc, W1l, b1l, W2l, b2l, onode);
    k_pool<<<NGRAPH, 256, 0, stream>>>(onode, bat, out);
}

// Round 4
// 846.366 us; speedup vs baseline: 2.2111x; 1.4540x over previous
//
#include <hip/hip_runtime.h>
#include <hip/hip_bf16.h>

#define N_NODES 100000
#define N_EDGES 1600000
#define FEAT 64
#define NGRAPH 256

#define SCAN_CHUNK 1024
#define SCAN_BLOCKS ((N_NODES + SCAN_CHUNK - 1) / SCAN_CHUNK)  // 98

// ---------------- CSR build ----------------

__global__ void k_hist(const int* __restrict__ dst, int* __restrict__ deg) {
    int e = blockIdx.x * blockDim.x + threadIdx.x;
    if (e < N_EDGES) atomicAdd(&deg[dst[e]], 1);
}

// Phase 1: per-block sums of 1024-element chunks.
__global__ __launch_bounds__(256) void k_scan1(const int* __restrict__ deg,
                                               int* __restrict__ bsum) {
    int t = threadIdx.x;
    int base = blockIdx.x * SCAN_CHUNK + t * 4;
    int4 d = make_int4(0, 0, 0, 0);
    if (base + 3 < N_NODES) {
        d = *reinterpret_cast<const int4*>(&deg[base]);
    } else {
        if (base + 0 < N_NODES) d.x = deg[base + 0];
        if (base + 1 < N_NODES) d.y = deg[base + 1];
        if (base + 2 < N_NODES) d.z = deg[base + 2];
    }
    int v = d.x + d.y + d.z + d.w;
#pragma unroll
    for (int off = 32; off; off >>= 1) v += __shfl_xor(v, off);
    __shared__ int red[4];
    int lane = t & 63, wid = t >> 6;
    if (lane == 0) red[wid] = v;
    __syncthreads();
    if (t == 0) bsum[blockIdx.x] = red[0] + red[1] + red[2] + red[3];
}

// Phase 2: exclusive scan of the 98 block sums (single tiny block).
__global__ __launch_bounds__(128) void k_scan2(int* __restrict__ bsum) {
    __shared__ int s[128];
    int t = threadIdx.x;
    int v = (t < SCAN_BLOCKS) ? bsum[t] : 0;
    s[t] = v;
    __syncthreads();
    for (int off = 1; off < 128; off <<= 1) {
        int add = (t >= off) ? s[t - off] : 0;
        __syncthreads();
        s[t] += add;
        __syncthreads();
    }
    if (t < SCAN_BLOCKS) bsum[t] = (t ? s[t - 1] : 0);
}

// Phase 3: block-local exclusive scan + block prefix -> offs, curs.
__global__ __launch_bounds__(256) void k_scan3(int* __restrict__ deg_off,
                                               int* __restrict__ cursor,
                                               const int* __restrict__ bsum) {
    int t = threadIdx.x;
    int base = blockIdx.x * SCAN_CHUNK + t * 4;
    int4 d = make_int4(0, 0, 0, 0);
    bool full = (base + 3 < N_NODES);
    if (full) {
        d = *reinterpret_cast<const int4*>(&deg_off[base]);
    } else {
        if (base + 0 < N_NODES) d.x = deg_off[base + 0];
        if (base + 1 < N_NODES) d.y = deg_off[base + 1];
        if (base + 2 < N_NODES) d.z = deg_off[base + 2];
    }
    int total = d.x + d.y + d.z + d.w;
    __shared__ int sc[256];
    sc[t] = total;
    __syncthreads();
    for (int off = 1; off < 256; off <<= 1) {
        int add = (t >= off) ? sc[t - off] : 0;
        __syncthreads();
        sc[t] += add;
        __syncthreads();
    }
    int texc = (t ? sc[t - 1] : 0) + bsum[blockIdx.x];
    int4 o;
    o.x = texc;
    o.y = o.x + d.x;
    o.z = o.y + d.y;
    o.w = o.z + d.z;
    if (full) {
        *reinterpret_cast<int4*>(&deg_off[base]) = o;
        *reinterpret_cast<int4*>(&cursor[base]) = o;
    } else {
        if (base + 0 < N_NODES) { deg_off[base + 0] = o.x; cursor[base + 0] = o.x; }
        if (base + 1 < N_NODES) { deg_off[base + 1] = o.y; cursor[base + 1] = o.y; }
        if (base + 2 < N_NODES) { deg_off[base + 2] = o.z; cursor[base + 2] = o.z; }
    }
}

__global__ void k_scatter(const int* __restrict__ src, const int* __restrict__ dst,
                          int* __restrict__ cursor, int* __restrict__ ssrc) {
    int e = blockIdx.x * blockDim.x + threadIdx.x;
    if (e < N_EDGES) {
        int pos = atomicAdd(&cursor[dst[e]], 1);
        ssrc[pos] = src[e];
    }
}

// ---------------- GIN aggregation: agg[i] = h[i] + sum_{j in N(i)} h[src_j] ----------------
// wave per node; lane = feature.

__global__ __launch_bounds__(256) void k_aggregate(const float* __restrict__ hin,
                                                   float* __restrict__ agg,
                                                   const int* __restrict__ offs,
                                                   const int* __restrict__ ends,
                                                   const int* __restrict__ ssrc) {
    int node = blockIdx.x * 4 + (threadIdx.x >> 6);
    int lane = threadIdx.x & 63;
    if (node >= N_NODES) return;
    float v = hin[node * FEAT + lane];
    int s = offs[node], e = ends[node];
    int j = s;
    for (; j + 1 < e; j += 2) {
        int s0 = ssrc[j], s1 = ssrc[j + 1];
        float a0 = hin[s0 * FEAT + lane];
        float a1 = hin[s1 * FEAT + lane];
        v += a0;
        v += a1;
    }
    if (j < e) v += hin[ssrc[j] * FEAT + lane];
    agg[node * FEAT + lane] = v;
}

// ---------------- fused 64->64->64 MLP, thread-per-node, no shuffles ----------------
// Weights staged raw (row-major) in LDS; inner loops read one weight ROW as
// uniform ds_read_b128 (broadcast, conflict-free) feeding 4 FMAs each.

template <bool RELU_OUT>
__global__ __launch_bounds__(256) void k_mlp(const float* __restrict__ agg,
                                             float* __restrict__ hout,
                                             const float* __restrict__ W1,
                                             const float* __restrict__ b1,
                                             const float* __restrict__ W2,
                                             const float* __restrict__ b2) {
    __shared__ float w1s[FEAT * FEAT];
    __shared__ float w2s[FEAT * FEAT];
    __shared__ float b1s[FEAT];
    __shared__ float b2s[FEAT];
    {
        const float4* W1v = (const float4*)W1;
        const float4* W2v = (const float4*)W2;
        float4* w1sv = (float4*)w1s;
        float4* w2sv = (float4*)w2s;
        for (int i = threadIdx.x; i < FEAT * FEAT / 4; i += 256) {
            w1sv[i] = W1v[i];
            w2sv[i] = W2v[i];
        }
        if (threadIdx.x < FEAT) {
            b1s[threadIdx.x] = b1[threadIdx.x];
            b2s[threadIdx.x] = b2[threadIdx.x];
        }
    }
    __syncthreads();

    int node = blockIdx.x * 256 + threadIdx.x;
    if (node >= N_NODES) return;

    float a[FEAT], h[FEAT];
    const float4* av = (const float4*)(agg + (size_t)node * FEAT);
#pragma unroll
    for (int q = 0; q < FEAT / 4; ++q) {
        float4 v = av[q];
        a[4 * q + 0] = v.x; a[4 * q + 1] = v.y; a[4 * q + 2] = v.z; a[4 * q + 3] = v.w;
    }

    // layer 1: h = relu(W1^T a + b1)   (h_j = sum_k a_k * W1[k][j])
    const float4* w1v = (const float4*)w1s;
    const float4* b1v = (const float4*)b1s;
#pragma unroll
    for (int q = 0; q < FEAT / 4; ++q) {
        float4 b = b1v[q];
        h[4 * q + 0] = b.x; h[4 * q + 1] = b.y; h[4 * q + 2] = b.z; h[4 * q + 3] = b.w;
    }
#pragma unroll
    for (int k = 0; k < FEAT; ++k) {
        float ak = a[k];
#pragma unroll
        for (int q = 0; q < FEAT / 4; ++q) {
            float4 w = w1v[k * (FEAT / 4) + q];
            h[4 * q + 0] = fmaf(ak, w.x, h[4 * q + 0]);
            h[4 * q + 1] = fmaf(ak, w.y, h[4 * q + 1]);
            h[4 * q + 2] = fmaf(ak, w.z, h[4 * q + 2]);
            h[4 * q + 3] = fmaf(ak, w.w, h[4 * q + 3]);
        }
    }
#pragma unroll
    for (int j = 0; j < FEAT; ++j) h[j] = fmaxf(h[j], 0.0f);

    // layer 2: o = W2^T h + b2, reusing a[] as accumulators
    const float4* w2v = (const float4*)w2s;
    const float4* b2v = (const float4*)b2s;
#pragma unroll
    for (int q = 0; q < FEAT / 4; ++q) {
        float4 b = b2v[q];
        a[4 * q + 0] = b.x; a[4 * q + 1] = b.y; a[4 * q + 2] = b.z; a[4 * q + 3] = b.w;
    }
#pragma unroll
    for (int k = 0; k < FEAT; ++k) {
        float hk = h[k];
#pragma unroll
        for (int q = 0; q < FEAT / 4; ++q) {
            float4 w = w2v[k * (FEAT / 4) + q];
            a[4 * q + 0] = fmaf(hk, w.x, a[4 * q + 0]);
            a[4 * q + 1] = fmaf(hk, w.y, a[4 * q + 1]);
            a[4 * q + 2] = fmaf(hk, w.z, a[4 * q + 2]);
            a[4 * q + 3] = fmaf(hk, w.w, a[4 * q + 3]);
        }
    }
    if (RELU_OUT) {
#pragma unroll
        for (int j = 0; j < FEAT; ++j) a[j] = fmaxf(a[j], 0.0f);
    }

    float4* ov = (float4*)(hout + (size_t)node * FEAT);
#pragma unroll
    for (int q = 0; q < FEAT / 4; ++q)
        ov[q] = make_float4(a[4 * q + 0], a[4 * q + 1], a[4 * q + 2], a[4 * q + 3]);
}

// ---------------- last layer: fused aggregate + (64->1->1) MLP -> scalar per node ----------------

__global__ __launch_bounds__(256) void k_lastagg(const float* __restrict__ hin,
                                                 const int* __restrict__ offs,
                                                 const int* __restrict__ ends,
                                                 const int* __restrict__ ssrc,
                                                 const float* __restrict__ W1l,
                                                 const float* __restrict__ b1l,
                                                 const float* __restrict__ W2l,
                                                 const float* __restrict__ b2l,
                                                 float* __restrict__ o) {
    int node = blockIdx.x * 4 + (threadIdx.x >> 6);
    int lane = threadIdx.x & 63;
    if (node >= N_NODES) return;
    float v = hin[node * FEAT + lane];
    int s = offs[node], e = ends[node];
    int j = s;
    for (; j + 1 < e; j += 2) {
        int s0 = ssrc[j], s1 = ssrc[j + 1];
        v += hin[s0 * FEAT + lane];
        v += hin[s1 * FEAT + lane];
    }
    if (j < e) v += hin[ssrc[j] * FEAT + lane];
    v *= W1l[lane];
#pragma unroll
    for (int off = 32; off; off >>= 1) v += __shfl_xor(v, off);
    if (lane == 0) {
        float h1 = fmaxf(v + b1l[0], 0.0f);
        o[node] = fmaf(h1, W2l[0], b2l[0]);
    }
}

// ---------------- mean pool: one block per graph, sorted batch, binary search ----------------

__global__ __launch_bounds__(256) void k_pool(const float* __restrict__ o,
                                              const int* __restrict__ batch,
                                              float* __restrict__ out) {
    int g = blockIdx.x;
    int lo = 0, hi = N_NODES;
    while (lo < hi) { int mid = (lo + hi) >> 1; if (batch[mid] < g) lo = mid + 1; else hi = mid; }
    int start = lo;
    hi = N_NODES;
    while (lo < hi) { int mid = (lo + hi) >> 1; if (batch[mid] < g + 1) lo = mid + 1; else hi = mid; }
    int end = lo;

    float s = 0.0f;
    for (int i = start + threadIdx.x; i < end; i += 256) s += o[i];
#pragma unroll
    for (int off = 32; off; off >>= 1) s += __shfl_xor(s, off);
    __shared__ float red[4];
    int lane = threadIdx.x & 63, wid = threadIdx.x >> 6;
    if (lane == 0) red[wid] = s;
    __syncthreads();
    if (threadIdx.x == 0) {
        float t = red[0] + red[1] + red[2] + red[3];
        float c = (float)(end - start);
        out[g] = t / fmaxf(c, 1.0f);
    }
}

// ---------------- launch ----------------

extern "C" void kernel_launch(void* const* d_in, const int* in_sizes, int n_in,
                              void* d_out, int out_size, void* d_ws, size_t ws_size,
                              hipStream_t stream) {
    const float* x    = (const float*)d_in[0];
    const int*   ei   = (const int*)d_in[1];   // [2][N_EDGES]
    const int*   bat  = (const int*)d_in[2];
    const float* W1   = (const float*)d_in[3]; // [4][64][64]
    const float* b1   = (const float*)d_in[4]; // [4][64]
    const float* W2   = (const float*)d_in[5];
    const float* b2   = (const float*)d_in[6];
    const float* W1l  = (const float*)d_in[7];
    const float* b1l  = (const float*)d_in[8];
    const float* W2l  = (const float*)d_in[9];
    const float* b2l  = (const float*)d_in[10];
    float* out = (float*)d_out;

    const int* srcI = ei;            // row 0
    const int* dstI = ei + N_EDGES;  // row 1

    // workspace carve-up (all 16B-aligned)
    char* ws = (char*)d_ws;
    float* agg   = (float*)ws;                              ws += (size_t)N_NODES * FEAT * 4;
    float* h     = (float*)ws;                              ws += (size_t)N_NODES * FEAT * 4;
    int*   offs  = (int*)ws;                                ws += (size_t)N_NODES * 4;
    int*   curs  = (int*)ws;                                ws += (size_t)N_NODES * 4;
    int*   ssrc  = (int*)ws;                                ws += (size_t)N_EDGES * 4;
    float* onode = (float*)ws;                              ws += (size_t)N_NODES * 4;
    int*   bsum  = (int*)ws;                                ws += 128 * 4;

    hipMemsetAsync(offs, 0, (size_t)N_NODES * 4, stream);

    const int EB = 256;
    const int egrid = (N_EDGES + EB - 1) / EB;
    k_hist<<<egrid, EB, 0, stream>>>(dstI, offs);
    k_scan1<<<SCAN_BLOCKS, 256, 0, stream>>>(offs, bsum);
    k_scan2<<<1, 128, 0, stream>>>(bsum);
    k_scan3<<<SCAN_BLOCKS, 256, 0, stream>>>(offs, curs, bsum);
    k_scatter<<<egrid, EB, 0, stream>>>(srcI, dstI, curs, ssrc);

    const int ngrid = (N_NODES + 3) / 4;      // aggregate: 4 nodes (waves) per block
    const int mgrid = (N_NODES + 255) / 256;  // mlp: thread per node

    // layers 0..3
    for (int l = 0; l < 4; ++l) {
        const float* hin = (l == 0) ? x : h;
        k_aggregate<<<ngrid, 256, 0, stream>>>(hin, agg, offs, curs, ssrc);
        k_mlp<true><<<mgrid, 256, 0, stream>>>(agg, h,
                                               W1 + (size_t)l * FEAT * FEAT,
                                               b1 + (size_t)l * FEAT,
                                               W2 + (size_t)l * FEAT * FEAT,
                                               b2 + (size_t)l * FEAT);
    }
    // last layer: fused aggregate + 64->1->1, then pool
    k_lastagg<<<ngrid, 256, 0, stream>>>(h, offs, curs, ssrc, W1l, b1l, W2l, b2l, onode);
    k_pool<<<NGRAPH, 256, 0, stream>>>(onode, bat, out);
}

// Round 5
// 745.785 us; speedup vs baseline: 2.5093x; 1.1349x over previous
//
#include <hip/hip_runtime.h>
#include <hip/hip_bf16.h>

#define N_NODES 100000
#define N_EDGES 1600000
#define FEAT 64
#define NGRAPH 256

#define SCAN_CHUNK 1024
#define SCAN_BLOCKS ((N_NODES + SCAN_CHUNK - 1) / SCAN_CHUNK)  // 98

#define BK_NODES 32                                            // nodes per bucket
#define N_BUCKETS ((N_NODES + BK_NODES - 1) / BK_NODES)        // 3125
#define BK_CAP 1024                                            // LDS sort capacity (avg 512)

typedef unsigned short u16;
typedef unsigned int u32;

static __device__ __forceinline__ float bf2f(u16 h) {
    return __uint_as_float(((u32)h) << 16);
}
static __device__ __forceinline__ u16 f2bf(float x) {  // round-to-nearest-even (finite)
    u32 u = __float_as_uint(x);
    return (u16)((u + 0x7FFF + ((u >> 16) & 1)) >> 16);
}

// ---------------- CSR build ----------------

__global__ void k_hist(const int* __restrict__ dst, int* __restrict__ deg) {
    int e = blockIdx.x * blockDim.x + threadIdx.x;
    if (e < N_EDGES) atomicAdd(&deg[dst[e]], 1);
}

__global__ __launch_bounds__(256) void k_scan1(const int* __restrict__ deg,
                                               int* __restrict__ bsum) {
    int t = threadIdx.x;
    int base = blockIdx.x * SCAN_CHUNK + t * 4;
    int4 d = make_int4(0, 0, 0, 0);
    if (base + 3 < N_NODES) {
        d = *reinterpret_cast<const int4*>(&deg[base]);
    } else {
        if (base + 0 < N_NODES) d.x = deg[base + 0];
        if (base + 1 < N_NODES) d.y = deg[base + 1];
        if (base + 2 < N_NODES) d.z = deg[base + 2];
    }
    int v = d.x + d.y + d.z + d.w;
#pragma unroll
    for (int off = 32; off; off >>= 1) v += __shfl_xor(v, off);
    __shared__ int red[4];
    int lane = t & 63, wid = t >> 6;
    if (lane == 0) red[wid] = v;
    __syncthreads();
    if (t == 0) bsum[blockIdx.x] = red[0] + red[1] + red[2] + red[3];
}

__global__ __launch_bounds__(128) void k_scan2(int* __restrict__ bsum) {
    __shared__ int s[128];
    int t = threadIdx.x;
    int v = (t < SCAN_BLOCKS) ? bsum[t] : 0;
    s[t] = v;
    __syncthreads();
    for (int off = 1; off < 128; off <<= 1) {
        int add = (t >= off) ? s[t - off] : 0;
        __syncthreads();
        s[t] += add;
        __syncthreads();
    }
    if (t < SCAN_BLOCKS) bsum[t] = (t ? s[t - 1] : 0);
}

__global__ __launch_bounds__(256) void k_scan3(int* __restrict__ deg_off,
                                               int* __restrict__ cursor,
                                               const int* __restrict__ bsum) {
    int t = threadIdx.x;
    int base = blockIdx.x * SCAN_CHUNK + t * 4;
    int4 d = make_int4(0, 0, 0, 0);
    bool full = (base + 3 < N_NODES);
    if (full) {
        d = *reinterpret_cast<const int4*>(&deg_off[base]);
    } else {
        if (base + 0 < N_NODES) d.x = deg_off[base + 0];
        if (base + 1 < N_NODES) d.y = deg_off[base + 1];
        if (base + 2 < N_NODES) d.z = deg_off[base + 2];
    }
    int total = d.x + d.y + d.z + d.w;
    __shared__ int sc[256];
    sc[t] = total;
    __syncthreads();
    for (int off = 1; off < 256; off <<= 1) {
        int add = (t >= off) ? sc[t - off] : 0;
        __syncthreads();
        sc[t] += add;
        __syncthreads();
    }
    int texc = (t ? sc[t - 1] : 0) + bsum[blockIdx.x];
    int4 o;
    o.x = texc;
    o.y = o.x + d.x;
    o.z = o.y + d.y;
    o.w = o.z + d.z;
    if (full) {
        *reinterpret_cast<int4*>(&deg_off[base]) = o;
        *reinterpret_cast<int4*>(&cursor[base]) = o;
    } else {
        if (base + 0 < N_NODES) { deg_off[base + 0] = o.x; cursor[base + 0] = o.x; }
        if (base + 1 < N_NODES) { deg_off[base + 1] = o.y; cursor[base + 1] = o.y; }
        if (base + 2 < N_NODES) { deg_off[base + 2] = o.z; cursor[base + 2] = o.z; }
    }
}

// bucket cursors = CSR offset of each bucket's first node
__global__ void k_binit(const int* __restrict__ offs, int* __restrict__ bcur) {
    int b = blockIdx.x * blockDim.x + threadIdx.x;
    if (b < N_BUCKETS) bcur[b] = offs[b * BK_NODES];
}

// partition edges into buckets: sequential per-bucket write streams (no line amplification)
__global__ void k_part(const int* __restrict__ src, const int* __restrict__ dst,
                       int* __restrict__ bcur, int* __restrict__ tmp) {
    int e = blockIdx.x * blockDim.x + threadIdx.x;
    if (e < N_EDGES) {
        int d = dst[e];
        int b = d >> 5;                      // /BK_NODES
        int packed = ((d & 31) << 17) | src[e];  // src < 2^17
        int pos = atomicAdd(&bcur[b], 1);
        tmp[pos] = packed;
    }
}

// per-bucket LDS counting sort -> exact CSR ssrc, coalesced write
__global__ __launch_bounds__(256) void k_bsort(const int* __restrict__ tmp,
                                               const int* __restrict__ offs,
                                               int* __restrict__ curs,
                                               int* __restrict__ ssrc) {
    int b = blockIdx.x;
    int firstNode = b * BK_NODES;
    int start = offs[firstNode];
    int end = (firstNode + BK_NODES >= N_NODES) ? N_EDGES : offs[firstNode + BK_NODES];
    int cnt = end - start;
    int t = threadIdx.x;

    if (cnt > BK_CAP) {  // statistically impossible overflow: old-style direct scatter
        for (int i = start + t; i < end; i += 256) {
            int p = tmp[i];
            int pos = atomicAdd(&curs[firstNode + (p >> 17)], 1);
            ssrc[pos] = p & 0x1FFFF;
        }
        return;
    }

    __shared__ int ebuf[BK_CAP];
    __shared__ int sbuf[BK_CAP];
    __shared__ int lcur[BK_NODES];
    if (t < BK_NODES) lcur[t] = 0;
    for (int i = t; i < cnt; i += 256) ebuf[i] = tmp[start + i];
    __syncthreads();
    for (int i = t; i < cnt; i += 256) atomicAdd(&lcur[ebuf[i] >> 17], 1);
    __syncthreads();
    if (t == 0) {
        int acc = 0;
#pragma unroll
        for (int j = 0; j < BK_NODES; ++j) { int c = lcur[j]; lcur[j] = acc; acc += c; }
    }
    __syncthreads();
    for (int i = t; i < cnt; i += 256) {
        int p = ebuf[i];
        int pos = atomicAdd(&lcur[p >> 17], 1);
        sbuf[pos] = p & 0x1FFFF;
    }
    __syncthreads();
    for (int i = t; i < cnt; i += 256) ssrc[start + i] = sbuf[i];
}

// ---------------- x (f32) -> bf16 node table ----------------

__global__ __launch_bounds__(256) void k_cvt(const float* __restrict__ x,
                                             u16* __restrict__ hb) {
    int i = blockIdx.x * 256 + threadIdx.x;  // 8 elems each
    const int total = N_NODES * FEAT / 8;    // 800000
    if (i < total) {
        const float4* xv = (const float4*)x;
        float4 a = xv[2 * i], b = xv[2 * i + 1];
        uint4 o;
        o.x = f2bf(a.x) | ((u32)f2bf(a.y) << 16);
        o.y = f2bf(a.z) | ((u32)f2bf(a.w) << 16);
        o.z = f2bf(b.x) | ((u32)f2bf(b.y) << 16);
        o.w = f2bf(b.z) | ((u32)f2bf(b.w) << 16);
        ((uint4*)hb)[i] = o;
    }
}

// ---------------- GIN aggregation (bf16 table -> f32 agg) ----------------

__global__ __launch_bounds__(256) void k_aggregate(const u16* __restrict__ hb,
                                                   float* __restrict__ agg,
                                                   const int* __restrict__ offs,
                                                   const int* __restrict__ ssrc) {
    int node = blockIdx.x * 4 + (threadIdx.x >> 6);
    int lane = threadIdx.x & 63;
    if (node >= N_NODES) return;
    float v = bf2f(hb[node * FEAT + lane]);
    int s = offs[node];
    int e = (node + 1 < N_NODES) ? offs[node + 1] : N_EDGES;
    int j = s;
    for (; j + 3 < e; j += 4) {
        int s0 = ssrc[j], s1 = ssrc[j + 1], s2 = ssrc[j + 2], s3 = ssrc[j + 3];
        float a0 = bf2f(hb[s0 * FEAT + lane]);
        float a1 = bf2f(hb[s1 * FEAT + lane]);
        float a2 = bf2f(hb[s2 * FEAT + lane]);
        float a3 = bf2f(hb[s3 * FEAT + lane]);
        v += a0; v += a1; v += a2; v += a3;
    }
    for (; j < e; ++j) v += bf2f(hb[ssrc[j] * FEAT + lane]);
    agg[node * FEAT + lane] = v;
}

// ---------------- fused 64->64->64 MLP (f32 math, bf16 output table) ----------------

template <bool RELU_OUT>
__global__ __launch_bounds__(256) void k_mlp(const float* __restrict__ agg,
                                             u16* __restrict__ hout,
                                             const float* __restrict__ W1,
                                             const float* __restrict__ b1,
                                             const float* __restrict__ W2,
                                             const float* __restrict__ b2) {
    __shared__ float w1s[FEAT * FEAT];
    __shared__ float w2s[FEAT * FEAT];
    __shared__ float b1s[FEAT];
    __shared__ float b2s[FEAT];
    {
        const float4* W1v = (const float4*)W1;
        const float4* W2v = (const float4*)W2;
        float4* w1sv = (float4*)w1s;
        float4* w2sv = (float4*)w2s;
        for (int i = threadIdx.x; i < FEAT * FEAT / 4; i += 256) {
            w1sv[i] = W1v[i];
            w2sv[i] = W2v[i];
        }
        if (threadIdx.x < FEAT) {
            b1s[threadIdx.x] = b1[threadIdx.x];
            b2s[threadIdx.x] = b2[threadIdx.x];
        }
    }
    __syncthreads();

    int node = blockIdx.x * 256 + threadIdx.x;
    if (node >= N_NODES) return;

    float a[FEAT], h[FEAT];
    const float4* av = (const float4*)(agg + (size_t)node * FEAT);
#pragma unroll
    for (int q = 0; q < FEAT / 4; ++q) {
        float4 v = av[q];
        a[4 * q + 0] = v.x; a[4 * q + 1] = v.y; a[4 * q + 2] = v.z; a[4 * q + 3] = v.w;
    }

    const float4* w1v = (const float4*)w1s;
    const float4* b1v = (const float4*)b1s;
#pragma unroll
    for (int q = 0; q < FEAT / 4; ++q) {
        float4 b = b1v[q];
        h[4 * q + 0] = b.x; h[4 * q + 1] = b.y; h[4 * q + 2] = b.z; h[4 * q + 3] = b.w;
    }
#pragma unroll
    for (int k = 0; k < FEAT; ++k) {
        float ak = a[k];
#pragma unroll
        for (int q = 0; q < FEAT / 4; ++q) {
            float4 w = w1v[k * (FEAT / 4) + q];
            h[4 * q + 0] = fmaf(ak, w.x, h[4 * q + 0]);
            h[4 * q + 1] = fmaf(ak, w.y, h[4 * q + 1]);
            h[4 * q + 2] = fmaf(ak, w.z, h[4 * q + 2]);
            h[4 * q + 3] = fmaf(ak, w.w, h[4 * q + 3]);
        }
    }
#pragma unroll
    for (int j = 0; j < FEAT; ++j) h[j] = fmaxf(h[j], 0.0f);

    const float4* w2v = (const float4*)w2s;
    const float4* b2v = (const float4*)b2s;
#pragma unroll
    for (int q = 0; q < FEAT / 4; ++q) {
        float4 b = b2v[q];
        a[4 * q + 0] = b.x; a[4 * q + 1] = b.y; a[4 * q + 2] = b.z; a[4 * q + 3] = b.w;
    }
#pragma unroll
    for (int k = 0; k < FEAT; ++k) {
        float hk = h[k];
#pragma unroll
        for (int q = 0; q < FEAT / 4; ++q) {
            float4 w = w2v[k * (FEAT / 4) + q];
            a[4 * q + 0] = fmaf(hk, w.x, a[4 * q + 0]);
            a[4 * q + 1] = fmaf(hk, w.y, a[4 * q + 1]);
            a[4 * q + 2] = fmaf(hk, w.z, a[4 * q + 2]);
            a[4 * q + 3] = fmaf(hk, w.w, a[4 * q + 3]);
        }
    }
    if (RELU_OUT) {
#pragma unroll
        for (int j = 0; j < FEAT; ++j) a[j] = fmaxf(a[j], 0.0f);
    }

    u32 w[FEAT / 2];
#pragma unroll
    for (int q = 0; q < FEAT / 2; ++q)
        w[q] = f2bf(a[2 * q]) | ((u32)f2bf(a[2 * q + 1]) << 16);
    uint4* ov = (uint4*)(hout + (size_t)node * FEAT);
#pragma unroll
    for (int q = 0; q < FEAT / 8; ++q)
        ov[q] = make_uint4(w[4 * q + 0], w[4 * q + 1], w[4 * q + 2], w[4 * q + 3]);
}

// ---------------- last layer: fused aggregate + (64->1->1) -> scalar per node ----------------

__global__ __launch_bounds__(256) void k_lastagg(const u16* __restrict__ hb,
                                                 const int* __restrict__ offs,
                                                 const int* __restrict__ ssrc,
                                                 const float* __restrict__ W1l,
                                                 const float* __restrict__ b1l,
                                                 const float* __restrict__ W2l,
                                                 const float* __restrict__ b2l,
                                                 float* __restrict__ o) {
    int node = blockIdx.x * 4 + (threadIdx.x >> 6);
    int lane = threadIdx.x & 63;
    if (node >= N_NODES) return;
    float v = bf2f(hb[node * FEAT + lane]);
    int s = offs[node];
    int e = (node + 1 < N_NODES) ? offs[node + 1] : N_EDGES;
    int j = s;
    for (; j + 1 < e; j += 2) {
        int s0 = ssrc[j], s1 = ssrc[j + 1];
        v += bf2f(hb[s0 * FEAT + lane]);
        v += bf2f(hb[s1 * FEAT + lane]);
    }
    if (j < e) v += bf2f(hb[ssrc[j] * FEAT + lane]);
    v *= W1l[lane];
#pragma unroll
    for (int off = 32; off; off >>= 1) v += __shfl_xor(v, off);
    if (lane == 0) {
        float h1 = fmaxf(v + b1l[0], 0.0f);
        o[node] = fmaf(h1, W2l[0], b2l[0]);
    }
}

// ---------------- mean pool ----------------

__global__ __launch_bounds__(256) void k_pool(const float* __restrict__ o,
                                              const int* __restrict__ batch,
                                              float* __restrict__ out) {
    int g = blockIdx.x;
    int lo = 0, hi = N_NODES;
    while (lo < hi) { int mid = (lo + hi) >> 1; if (batch[mid] < g) lo = mid + 1; else hi = mid; }
    int start = lo;
    hi = N_NODES;
    while (lo < hi) { int mid = (lo + hi) >> 1; if (batch[mid] < g + 1) lo = mid + 1; else hi = mid; }
    int end = lo;

    float s = 0.0f;
    for (int i = start + threadIdx.x; i < end; i += 256) s += o[i];
#pragma unroll
    for (int off = 32; off; off >>= 1) s += __shfl_xor(s, off);
    __shared__ float red[4];
    int lane = threadIdx.x & 63, wid = threadIdx.x >> 6;
    if (lane == 0) red[wid] = s;
    __syncthreads();
    if (threadIdx.x == 0) {
        float t = red[0] + red[1] + red[2] + red[3];
        float c = (float)(end - start);
        out[g] = t / fmaxf(c, 1.0f);
    }
}

// ---------------- launch ----------------

extern "C" void kernel_launch(void* const* d_in, const int* in_sizes, int n_in,
                              void* d_out, int out_size, void* d_ws, size_t ws_size,
                              hipStream_t stream) {
    const float* x    = (const float*)d_in[0];
    const int*   ei   = (const int*)d_in[1];   // [2][N_EDGES]
    const int*   bat  = (const int*)d_in[2];
    const float* W1   = (const float*)d_in[3];
    const float* b1   = (const float*)d_in[4];
    const float* W2   = (const float*)d_in[5];
    const float* b2   = (const float*)d_in[6];
    const float* W1l  = (const float*)d_in[7];
    const float* b1l  = (const float*)d_in[8];
    const float* W2l  = (const float*)d_in[9];
    const float* b2l  = (const float*)d_in[10];
    float* out = (float*)d_out;

    const int* srcI = ei;            // row 0
    const int* dstI = ei + N_EDGES;  // row 1

    // workspace carve-up (all 16B-aligned)
    char* ws = (char*)d_ws;
    float* agg   = (float*)ws;                              ws += (size_t)N_NODES * FEAT * 4;
    u16*   hb    = (u16*)ws;                                ws += (size_t)N_NODES * FEAT * 2;
    int*   offs  = (int*)ws;                                ws += (size_t)N_NODES * 4;
    int*   curs  = (int*)ws;                                ws += (size_t)N_NODES * 4;
    int*   ssrc  = (int*)ws;                                ws += (size_t)N_EDGES * 4;
    int*   tmp   = (int*)ws;                                ws += (size_t)N_EDGES * 4;
    float* onode = (float*)ws;                              ws += (size_t)N_NODES * 4;
    int*   bsum  = (int*)ws;                                ws += 128 * 4;
    int*   bcur  = (int*)ws;                                ws += ((N_BUCKETS + 3) & ~3) * 4;

    hipMemsetAsync(offs, 0, (size_t)N_NODES * 4, stream);

    const int EB = 256;
    const int egrid = (N_EDGES + EB - 1) / EB;
    k_hist<<<egrid, EB, 0, stream>>>(dstI, offs);
    k_scan1<<<SCAN_BLOCKS, 256, 0, stream>>>(offs, bsum);
    k_scan2<<<1, 128, 0, stream>>>(bsum);
    k_scan3<<<SCAN_BLOCKS, 256, 0, stream>>>(offs, curs, bsum);
    k_binit<<<(N_BUCKETS + 255) / 256, 256, 0, stream>>>(offs, bcur);
    k_part<<<egrid, EB, 0, stream>>>(srcI, dstI, bcur, tmp);
    k_bsort<<<N_BUCKETS, 256, 0, stream>>>(tmp, offs, curs, ssrc);
    k_cvt<<<(N_NODES * FEAT / 8 + 255) / 256, 256, 0, stream>>>(x, hb);

    const int ngrid = (N_NODES + 3) / 4;      // aggregate: 4 nodes (waves) per block
    const int mgrid = (N_NODES + 255) / 256;  // mlp: thread per node

    for (int l = 0; l < 4; ++l) {
        k_aggregate<<<ngrid, 256, 0, stream>>>(hb, agg, offs, ssrc);
        k_mlp<true><<<mgrid, 256, 0, stream>>>(agg, hb,
                                               W1 + (size_t)l * FEAT * FEAT,
                                               b1 + (size_t)l * FEAT,
                                               W2 + (size_t)l * FEAT * FEAT,
                                               b2 + (size_t)l * FEAT);
    }
    k_lastagg<<<ngrid, 256, 0, stream>>>(hb, offs, ssrc, W1l, b1l, W2l, b2l, onode);
    k_pool<<<NGRAPH, 256, 0, stream>>>(onode, bat, out);
}

// Round 6
// 623.702 us; speedup vs baseline: 3.0005x; 1.1957x over previous
//
#include <hip/hip_runtime.h>
#include <hip/hip_bf16.h>

#define N_NODES 100000
#define N_EDGES 1600000
#define FEAT 64
#define NGRAPH 256

#define SCAN_CHUNK 1024
#define SCAN_BLOCKS ((N_NODES + SCAN_CHUNK - 1) / SCAN_CHUNK)  // 98

// coarse buckets for partition: 1024 nodes each
#define CB_SHIFT 10
#define CB_NODES 1024
#define NCB ((N_NODES + CB_NODES - 1) / CB_NODES)   // 98
#define CB_CAP 18432                                 // slots per bucket (mean 16327, +16 sigma)
#define STAGE_CAP 32                                 // LDS staged entries per bucket
#define PART_BLOCKS 256

typedef unsigned short u16;
typedef unsigned int u32;

static __device__ __forceinline__ float bf2f(u16 h) {
    return __uint_as_float(((u32)h) << 16);
}
static __device__ __forceinline__ u16 f2bf(float x) {  // round-to-nearest-even (finite)
    u32 u = __float_as_uint(x);
    return (u16)((u + 0x7FFF + ((u >> 16) & 1)) >> 16);
}

// ---------------- CSR build ----------------

__global__ void k_hist(const int* __restrict__ dst, int* __restrict__ deg) {
    int e = blockIdx.x * blockDim.x + threadIdx.x;
    if (e < N_EDGES) atomicAdd(&deg[dst[e]], 1);
}

__global__ __launch_bounds__(256) void k_scan1(const int* __restrict__ deg,
                                               int* __restrict__ bsum) {
    int t = threadIdx.x;
    int base = blockIdx.x * SCAN_CHUNK + t * 4;
    int4 d = make_int4(0, 0, 0, 0);
    if (base + 3 < N_NODES) {
        d = *reinterpret_cast<const int4*>(&deg[base]);
    } else {
        if (base + 0 < N_NODES) d.x = deg[base + 0];
        if (base + 1 < N_NODES) d.y = deg[base + 1];
        if (base + 2 < N_NODES) d.z = deg[base + 2];
    }
    int v = d.x + d.y + d.z + d.w;
#pragma unroll
    for (int off = 32; off; off >>= 1) v += __shfl_xor(v, off);
    __shared__ int red[4];
    int lane = t & 63, wid = t >> 6;
    if (lane == 0) red[wid] = v;
    __syncthreads();
    if (t == 0) bsum[blockIdx.x] = red[0] + red[1] + red[2] + red[3];
}

__global__ __launch_bounds__(128) void k_scan2(int* __restrict__ bsum) {
    __shared__ int s[128];
    int t = threadIdx.x;
    int v = (t < SCAN_BLOCKS) ? bsum[t] : 0;
    s[t] = v;
    __syncthreads();
    for (int off = 1; off < 128; off <<= 1) {
        int add = (t >= off) ? s[t - off] : 0;
        __syncthreads();
        s[t] += add;
        __syncthreads();
    }
    if (t < SCAN_BLOCKS) bsum[t] = (t ? s[t - 1] : 0);
}

__global__ __launch_bounds__(256) void k_scan3(int* __restrict__ deg_off,
                                               int* __restrict__ cursor,
                                               const int* __restrict__ bsum) {
    int t = threadIdx.x;
    int base = blockIdx.x * SCAN_CHUNK + t * 4;
    int4 d = make_int4(0, 0, 0, 0);
    bool full = (base + 3 < N_NODES);
    if (full) {
        d = *reinterpret_cast<const int4*>(&deg_off[base]);
    } else {
        if (base + 0 < N_NODES) d.x = deg_off[base + 0];
        if (base + 1 < N_NODES) d.y = deg_off[base + 1];
        if (base + 2 < N_NODES) d.z = deg_off[base + 2];
    }
    int total = d.x + d.y + d.z + d.w;
    __shared__ int sc[256];
    sc[t] = total;
    __syncthreads();
    for (int off = 1; off < 256; off <<= 1) {
        int add = (t >= off) ? sc[t - off] : 0;
        __syncthreads();
        sc[t] += add;
        __syncthreads();
    }
    int texc = (t ? sc[t - 1] : 0) + bsum[blockIdx.x];
    int4 o;
    o.x = texc;
    o.y = o.x + d.x;
    o.z = o.y + d.y;
    o.w = o.z + d.z;
    if (full) {
        *reinterpret_cast<int4*>(&deg_off[base]) = o;
        *reinterpret_cast<int4*>(&cursor[base]) = o;
    } else {
        if (base + 0 < N_NODES) { deg_off[base + 0] = o.x; cursor[base + 0] = o.x; }
        if (base + 1 < N_NODES) { deg_off[base + 1] = o.y; cursor[base + 1] = o.y; }
        if (base + 2 < N_NODES) { deg_off[base + 2] = o.z; cursor[base + 2] = o.z; }
    }
}

// ---------------- partition: LDS-staged, full-64B-line flushes ----------------
// Every tmp line is written entirely by ONE thread (16-entry aligned groups),
// so no cross-XCD partial-line write amplification.

__global__ __launch_bounds__(256) void k_part(const int* __restrict__ src,
                                              const int* __restrict__ dst,
                                              int* __restrict__ gcur,
                                              int* __restrict__ tmp,
                                              int* __restrict__ curs,
                                              int* __restrict__ ssrc) {
    __shared__ int sbuf[NCB * STAGE_CAP];
    __shared__ int scnt[NCB];
    int t = threadIdx.x;
    for (int i = t; i < NCB; i += 256) scnt[i] = 0;
    __syncthreads();

    const int EPB = (N_EDGES + PART_BLOCKS - 1) / PART_BLOCKS;  // 6250
    int begin = blockIdx.x * EPB;
    int endE = begin + EPB; if (endE > N_EDGES) endE = N_EDGES;

    for (int base = begin; base < endE; base += 256) {
        int e = base + t;
        if (e < endE) {
            int d = dst[e];
            int b = d >> CB_SHIFT;
            int packed = ((d & (CB_NODES - 1)) << 17) | src[e];
            int pos = atomicAdd(&scnt[b], 1);
            if (pos < STAGE_CAP) sbuf[b * STAGE_CAP + pos] = packed;
            else {  // statistically-impossible stage overflow: direct node scatter
                int p2 = atomicAdd(&curs[d], 1);
                ssrc[p2] = src[e];
            }
        }
        __syncthreads();
        // flush full 16-entry groups (64B-aligned), compact residual
        for (int b = t; b < NCB; b += 256) {
            int c = scnt[b]; if (c > STAGE_CAP) c = STAGE_CAP;
            int nfl = c & ~15;
            if (nfl) {
                int* s0 = &sbuf[b * STAGE_CAP];
                int gp = atomicAdd(&gcur[b], nfl);
                if (gp + nfl <= CB_CAP) {
                    int4* dp = (int4*)&tmp[b * CB_CAP + gp];
                    for (int i = 0; i < nfl; i += 4)
                        dp[i >> 2] = make_int4(s0[i], s0[i + 1], s0[i + 2], s0[i + 3]);
                } else {  // bucket-capacity overflow (never in practice): salvage what fits
                    int fit = CB_CAP - gp; if (fit < 0) fit = 0;
                    for (int i = 0; i < nfl; ++i) {
                        int p = s0[i];
                        if (i < fit) tmp[b * CB_CAP + gp + i] = p;
                        else {
                            int node = (b << CB_SHIFT) + (p >> 17);
                            int p2 = atomicAdd(&curs[node], 1);
                            ssrc[p2] = p & 0x1FFFF;
                        }
                    }
                }
                int r = c - nfl;
                for (int i = 0; i < r; ++i) s0[i] = s0[nfl + i];
                scnt[b] = r;
            }
        }
        __syncthreads();
    }
    // final residual flush (<=15 entries per bucket -> at most one partial line each)
    for (int b = t; b < NCB; b += 256) {
        int r = scnt[b]; if (r > STAGE_CAP) r = STAGE_CAP;
        if (r) {
            int gp = atomicAdd(&gcur[b], r);
            for (int i = 0; i < r; ++i) {
                int p = sbuf[b * STAGE_CAP + i];
                if (gp + i < CB_CAP) tmp[b * CB_CAP + gp + i] = p;
                else {
                    int node = (b << CB_SHIFT) + (p >> 17);
                    int p2 = atomicAdd(&curs[node], 1);
                    ssrc[p2] = p & 0x1FFFF;
                }
            }
        }
    }
}

// ---------------- per-bucket scatter into CSR order (block-private region) ----------------

__global__ __launch_bounds__(256) void k_bsort(const int* __restrict__ tmp,
                                               const int* __restrict__ gcur,
                                               const int* __restrict__ curs,
                                               int* __restrict__ ssrc) {
    __shared__ int lcur[CB_NODES];
    int b = blockIdx.x;
    int n0 = b << CB_SHIFT;
    int t = threadIdx.x;
    for (int j = t; j < CB_NODES; j += 256) {
        int n = n0 + j;
        lcur[j] = (n < N_NODES) ? curs[n] : 0;
    }
    __syncthreads();
    int cnt = gcur[b]; if (cnt > CB_CAP) cnt = CB_CAP;
    const int* tp = &tmp[b * CB_CAP];
    for (int i = t; i < cnt; i += 256) {
        int p = tp[i];
        int pos = atomicAdd(&lcur[p >> 17], 1);
        ssrc[pos] = p & 0x1FFFF;
    }
}

// ---------------- x (f32) -> bf16 node table ----------------

__global__ __launch_bounds__(256) void k_cvt(const float* __restrict__ x,
                                             u16* __restrict__ hb) {
    int i = blockIdx.x * 256 + threadIdx.x;  // 8 elems each
    const int total = N_NODES * FEAT / 8;
    if (i < total) {
        const float4* xv = (const float4*)x;
        float4 a = xv[2 * i], b = xv[2 * i + 1];
        uint4 o;
        o.x = f2bf(a.x) | ((u32)f2bf(a.y) << 16);
        o.y = f2bf(a.z) | ((u32)f2bf(a.w) << 16);
        o.z = f2bf(b.x) | ((u32)f2bf(b.y) << 16);
        o.w = f2bf(b.z) | ((u32)f2bf(b.w) << 16);
        ((uint4*)hb)[i] = o;
    }
}

// ---------------- GIN aggregation: 2 nodes per wave, u32 (2 bf16) per lane ----------------

__global__ __launch_bounds__(256) void k_aggregate(const u16* __restrict__ hb,
                                                   float* __restrict__ agg,
                                                   const int* __restrict__ offs,
                                                   const int* __restrict__ ssrc) {
    int w = threadIdx.x >> 6;
    int lane = threadIdx.x & 63;
    int half = lane >> 5;
    int li = lane & 31;
    int node = blockIdx.x * 8 + w * 2 + half;
    if (node >= N_NODES) return;
    const u32* hb32 = (const u32*)hb;
    u32 pv = hb32[node * 32 + li];
    float v0 = bf2f((u16)(pv & 0xFFFF));
    float v1 = bf2f((u16)(pv >> 16));
    int s = offs[node];
    int e = (node + 1 < N_NODES) ? offs[node + 1] : N_EDGES;
    int j = s;
    for (; j + 3 < e; j += 4) {
        int s0 = ssrc[j], s1 = ssrc[j + 1], s2 = ssrc[j + 2], s3 = ssrc[j + 3];
        u32 n0 = hb32[s0 * 32 + li];
        u32 n1 = hb32[s1 * 32 + li];
        u32 n2 = hb32[s2 * 32 + li];
        u32 n3 = hb32[s3 * 32 + li];
        v0 += bf2f((u16)(n0 & 0xFFFF)); v1 += bf2f((u16)(n0 >> 16));
        v0 += bf2f((u16)(n1 & 0xFFFF)); v1 += bf2f((u16)(n1 >> 16));
        v0 += bf2f((u16)(n2 & 0xFFFF)); v1 += bf2f((u16)(n2 >> 16));
        v0 += bf2f((u16)(n3 & 0xFFFF)); v1 += bf2f((u16)(n3 >> 16));
    }
    for (; j < e; ++j) {
        u32 nv = hb32[ssrc[j] * 32 + li];
        v0 += bf2f((u16)(nv & 0xFFFF));
        v1 += bf2f((u16)(nv >> 16));
    }
    float2* outp = (float2*)(agg + (size_t)node * FEAT);
    outp[li] = make_float2(v0, v1);
}

// ---------------- fused 64->64->64 MLP (f32 math, bf16 output table) ----------------

template <bool RELU_OUT>
__global__ __launch_bounds__(256) void k_mlp(const float* __restrict__ agg,
                                             u16* __restrict__ hout,
                                             const float* __restrict__ W1,
                                             const float* __restrict__ b1,
                                             const float* __restrict__ W2,
                                             const float* __restrict__ b2) {
    __shared__ float w1s[FEAT * FEAT];
    __shared__ float w2s[FEAT * FEAT];
    __shared__ float b1s[FEAT];
    __shared__ float b2s[FEAT];
    {
        const float4* W1v = (const float4*)W1;
        const float4* W2v = (const float4*)W2;
        float4* w1sv = (float4*)w1s;
        float4* w2sv = (float4*)w2s;
        for (int i = threadIdx.x; i < FEAT * FEAT / 4; i += 256) {
            w1sv[i] = W1v[i];
            w2sv[i] = W2v[i];
        }
        if (threadIdx.x < FEAT) {
            b1s[threadIdx.x] = b1[threadIdx.x];
            b2s[threadIdx.x] = b2[threadIdx.x];
        }
    }
    __syncthreads();

    int node = blockIdx.x * 256 + threadIdx.x;
    if (node >= N_NODES) return;

    float a[FEAT], h[FEAT];
    const float4* av = (const float4*)(agg + (size_t)node * FEAT);
#pragma unroll
    for (int q = 0; q < FEAT / 4; ++q) {
        float4 v = av[q];
        a[4 * q + 0] = v.x; a[4 * q + 1] = v.y; a[4 * q + 2] = v.z; a[4 * q + 3] = v.w;
    }

    const float4* w1v = (const float4*)w1s;
    const float4* b1v = (const float4*)b1s;
#pragma unroll
    for (int q = 0; q < FEAT / 4; ++q) {
        float4 b = b1v[q];
        h[4 * q + 0] = b.x; h[4 * q + 1] = b.y; h[4 * q + 2] = b.z; h[4 * q + 3] = b.w;
    }
#pragma unroll
    for (int k = 0; k < FEAT; ++k) {
        float ak = a[k];
#pragma unroll
        for (int q = 0; q < FEAT / 4; ++q) {
            float4 w = w1v[k * (FEAT / 4) + q];
            h[4 * q + 0] = fmaf(ak, w.x, h[4 * q + 0]);
            h[4 * q + 1] = fmaf(ak, w.y, h[4 * q + 1]);
            h[4 * q + 2] = fmaf(ak, w.z, h[4 * q + 2]);
            h[4 * q + 3] = fmaf(ak, w.w, h[4 * q + 3]);
        }
    }
#pragma unroll
    for (int j = 0; j < FEAT; ++j) h[j] = fmaxf(h[j], 0.0f);

    const float4* w2v = (const float4*)w2s;
    const float4* b2v = (const float4*)b2s;
#pragma unroll
    for (int q = 0; q < FEAT / 4; ++q) {
        float4 b = b2v[q];
        a[4 * q + 0] = b.x; a[4 * q + 1] = b.y; a[4 * q + 2] = b.z; a[4 * q + 3] = b.w;
    }
#pragma unroll
    for (int k = 0; k < FEAT; ++k) {
        float hk = h[k];
#pragma unroll
        for (int q = 0; q < FEAT / 4; ++q) {
            float4 w = w2v[k * (FEAT / 4) + q];
            a[4 * q + 0] = fmaf(hk, w.x, a[4 * q + 0]);
            a[4 * q + 1] = fmaf(hk, w.y, a[4 * q + 1]);
            a[4 * q + 2] = fmaf(hk, w.z, a[4 * q + 2]);
            a[4 * q + 3] = fmaf(hk, w.w, a[4 * q + 3]);
        }
    }
    if (RELU_OUT) {
#pragma unroll
        for (int j = 0; j < FEAT; ++j) a[j] = fmaxf(a[j], 0.0f);
    }

    u32 w[FEAT / 2];
#pragma unroll
    for (int q = 0; q < FEAT / 2; ++q)
        w[q] = f2bf(a[2 * q]) | ((u32)f2bf(a[2 * q + 1]) << 16);
    uint4* ov = (uint4*)(hout + (size_t)node * FEAT);
#pragma unroll
    for (int q = 0; q < FEAT / 8; ++q)
        ov[q] = make_uint4(w[4 * q + 0], w[4 * q + 1], w[4 * q + 2], w[4 * q + 3]);
}

// ---------------- last layer: fused aggregate + (64->1->1) -> scalar per node ----------------

__global__ __launch_bounds__(256) void k_lastagg(const u16* __restrict__ hb,
                                                 const int* __restrict__ offs,
                                                 const int* __restrict__ ssrc,
                                                 const float* __restrict__ W1l,
                                                 const float* __restrict__ b1l,
                                                 const float* __restrict__ W2l,
                                                 const float* __restrict__ b2l,
                                                 float* __restrict__ o) {
    int w = threadIdx.x >> 6;
    int lane = threadIdx.x & 63;
    int half = lane >> 5;
    int li = lane & 31;
    int node = blockIdx.x * 8 + w * 2 + half;
    if (node >= N_NODES) return;
    const u32* hb32 = (const u32*)hb;
    u32 pv = hb32[node * 32 + li];
    float v0 = bf2f((u16)(pv & 0xFFFF));
    float v1 = bf2f((u16)(pv >> 16));
    int s = offs[node];
    int e = (node + 1 < N_NODES) ? offs[node + 1] : N_EDGES;
    int j = s;
    for (; j + 1 < e; j += 2) {
        u32 n0 = hb32[ssrc[j] * 32 + li];
        u32 n1 = hb32[ssrc[j + 1] * 32 + li];
        v0 += bf2f((u16)(n0 & 0xFFFF)); v1 += bf2f((u16)(n0 >> 16));
        v0 += bf2f((u16)(n1 & 0xFFFF)); v1 += bf2f((u16)(n1 >> 16));
    }
    if (j < e) {
        u32 nv = hb32[ssrc[j] * 32 + li];
        v0 += bf2f((u16)(nv & 0xFFFF));
        v1 += bf2f((u16)(nv >> 16));
    }
    float v = v0 * W1l[2 * li] + v1 * W1l[2 * li + 1];
#pragma unroll
    for (int off = 16; off; off >>= 1) v += __shfl_xor(v, off);  // within 32-lane half
    if (li == 0) {
        float h1 = fmaxf(v + b1l[0], 0.0f);
        o[node] = fmaf(h1, W2l[0], b2l[0]);
    }
}

// ---------------- mean pool ----------------

__global__ __launch_bounds__(256) void k_pool(const float* __restrict__ o,
                                              const int* __restrict__ batch,
                                              float* __restrict__ out) {
    int g = blockIdx.x;
    int lo = 0, hi = N_NODES;
    while (lo < hi) { int mid = (lo + hi) >> 1; if (batch[mid] < g) lo = mid + 1; else hi = mid; }
    int start = lo;
    hi = N_NODES;
    while (lo < hi) { int mid = (lo + hi) >> 1; if (batch[mid] < g + 1) lo = mid + 1; else hi = mid; }
    int end = lo;

    float s = 0.0f;
    for (int i = start + threadIdx.x; i < end; i += 256) s += o[i];
#pragma unroll
    for (int off = 32; off; off >>= 1) s += __shfl_xor(s, off);
    __shared__ float red[4];
    int lane = threadIdx.x & 63, wid = threadIdx.x >> 6;
    if (lane == 0) red[wid] = s;
    __syncthreads();
    if (threadIdx.x == 0) {
        float t = red[0] + red[1] + red[2] + red[3];
        float c = (float)(end - start);
        out[g] = t / fmaxf(c, 1.0f);
    }
}

// ---------------- launch ----------------

extern "C" void kernel_launch(void* const* d_in, const int* in_sizes, int n_in,
                              void* d_out, int out_size, void* d_ws, size_t ws_size,
                              hipStream_t stream) {
    const float* x    = (const float*)d_in[0];
    const int*   ei   = (const int*)d_in[1];   // [2][N_EDGES]
    const int*   bat  = (const int*)d_in[2];
    const float* W1   = (const float*)d_in[3];
    const float* b1   = (const float*)d_in[4];
    const float* W2   = (const float*)d_in[5];
    const float* b2   = (const float*)d_in[6];
    const float* W1l  = (const float*)d_in[7];
    const float* b1l  = (const float*)d_in[8];
    const float* W2l  = (const float*)d_in[9];
    const float* b2l  = (const float*)d_in[10];
    float* out = (float*)d_out;

    const int* srcI = ei;            // row 0
    const int* dstI = ei + N_EDGES;  // row 1

    // workspace carve-up (all 16B-aligned)
    char* ws = (char*)d_ws;
    float* agg   = (float*)ws;                              ws += (size_t)N_NODES * FEAT * 4;
    u16*   hb    = (u16*)ws;                                ws += (size_t)N_NODES * FEAT * 2;
    int*   offs  = (int*)ws;                                ws += (size_t)N_NODES * 4;
    int*   curs  = (int*)ws;                                ws += (size_t)N_NODES * 4;
    int*   ssrc  = (int*)ws;                                ws += (size_t)N_EDGES * 4;
    int*   tmp   = (int*)ws;                                ws += (size_t)NCB * CB_CAP * 4;
    float* onode = (float*)ws;                              ws += (size_t)N_NODES * 4;
    int*   bsum  = (int*)ws;                                ws += 128 * 4;
    int*   gcur  = (int*)ws;                                ws += ((NCB + 3) & ~3) * 4;

    hipMemsetAsync(offs, 0, (size_t)N_NODES * 4, stream);
    hipMemsetAsync(gcur, 0, (size_t)NCB * 4, stream);

    const int EB = 256;
    const int egrid = (N_EDGES + EB - 1) / EB;
    k_hist<<<egrid, EB, 0, stream>>>(dstI, offs);
    k_scan1<<<SCAN_BLOCKS, 256, 0, stream>>>(offs, bsum);
    k_scan2<<<1, 128, 0, stream>>>(bsum);
    k_scan3<<<SCAN_BLOCKS, 256, 0, stream>>>(offs, curs, bsum);
    k_part<<<PART_BLOCKS, 256, 0, stream>>>(srcI, dstI, gcur, tmp, curs, ssrc);
    k_bsort<<<NCB, 256, 0, stream>>>(tmp, gcur, curs, ssrc);
    k_cvt<<<(N_NODES * FEAT / 8 + 255) / 256, 256, 0, stream>>>(x, hb);

    const int ngrid = (N_NODES + 7) / 8;      // aggregate: 8 nodes (2 per wave) per block
    const int mgrid = (N_NODES + 255) / 256;  // mlp: thread per node

    for (int l = 0; l < 4; ++l) {
        k_aggregate<<<ngrid, 256, 0, stream>>>(hb, agg, offs, ssrc);
        k_mlp<true><<<mgrid, 256, 0, stream>>>(agg, hb,
                                               W1 + (size_t)l * FEAT * FEAT,
                                               b1 + (size_t)l * FEAT,
                                               W2 + (size_t)l * FEAT * FEAT,
                                               b2 + (size_t)l * FEAT);
    }
    k_lastagg<<<ngrid, 256, 0, stream>>>(hb, offs, ssrc, W1l, b1l, W2l, b2l, onode);
    k_pool<<<NGRAPH, 256, 0, stream>>>(onode, bat, out);
}

// Round 7
// 531.849 us; speedup vs baseline: 3.5187x; 1.1727x over previous
//
#include <hip/hip_runtime.h>
#include <hip/hip_bf16.h>

#define N_NODES 100000
#define N_EDGES 1600000
#define FEAT 64
#define NGRAPH 256

#define SCAN_CHUNK 1024
#define SCAN_BLOCKS ((N_NODES + SCAN_CHUNK - 1) / SCAN_CHUNK)  // 98

// coarse buckets: 1024 nodes each
#define CB_SHIFT 10
#define CB_NODES 1024
#define NCB ((N_NODES + CB_NODES - 1) / CB_NODES)   // 98
#define CB_CAP 18432                                 // slots per bucket (mean 16384, +16 sigma)

#define PB 512                                       // partition blocks
#define EPB ((N_EDGES + PB - 1) / PB)                // 3125 edges per block

typedef unsigned short u16;
typedef unsigned int u32;

static __device__ __forceinline__ float bf2f(u16 h) {
    return __uint_as_float(((u32)h) << 16);
}
static __device__ __forceinline__ u16 f2bf(float x) {  // round-to-nearest-even (finite)
    u32 u = __float_as_uint(x);
    return (u16)((u + 0x7FFF + ((u >> 16) & 1)) >> 16);
}

// ---------------- CSR build ----------------

__global__ void k_hist(const int* __restrict__ dst, int* __restrict__ deg) {
    int e = blockIdx.x * blockDim.x + threadIdx.x;
    if (e < N_EDGES) atomicAdd(&deg[dst[e]], 1);
}

__global__ __launch_bounds__(256) void k_scan1(const int* __restrict__ deg,
                                               int* __restrict__ bsum) {
    int t = threadIdx.x;
    int base = blockIdx.x * SCAN_CHUNK + t * 4;
    int4 d = make_int4(0, 0, 0, 0);
    if (base + 3 < N_NODES) {
        d = *reinterpret_cast<const int4*>(&deg[base]);
    } else {
        if (base + 0 < N_NODES) d.x = deg[base + 0];
        if (base + 1 < N_NODES) d.y = deg[base + 1];
        if (base + 2 < N_NODES) d.z = deg[base + 2];
    }
    int v = d.x + d.y + d.z + d.w;
#pragma unroll
    for (int off = 32; off; off >>= 1) v += __shfl_xor(v, off);
    __shared__ int red[4];
    int lane = t & 63, wid = t >> 6;
    if (lane == 0) red[wid] = v;
    __syncthreads();
    if (t == 0) bsum[blockIdx.x] = red[0] + red[1] + red[2] + red[3];
}

__global__ __launch_bounds__(128) void k_scan2(int* __restrict__ bsum) {
    __shared__ int s[128];
    int t = threadIdx.x;
    int v = (t < SCAN_BLOCKS) ? bsum[t] : 0;
    s[t] = v;
    __syncthreads();
    for (int off = 1; off < 128; off <<= 1) {
        int add = (t >= off) ? s[t - off] : 0;
        __syncthreads();
        s[t] += add;
        __syncthreads();
    }
    if (t < SCAN_BLOCKS) bsum[t] = (t ? s[t - 1] : 0);
}

__global__ __launch_bounds__(256) void k_scan3(int* __restrict__ deg_off,
                                               const int* __restrict__ bsum) {
    int t = threadIdx.x;
    int base = blockIdx.x * SCAN_CHUNK + t * 4;
    int4 d = make_int4(0, 0, 0, 0);
    bool full = (base + 3 < N_NODES);
    if (full) {
        d = *reinterpret_cast<const int4*>(&deg_off[base]);
    } else {
        if (base + 0 < N_NODES) d.x = deg_off[base + 0];
        if (base + 1 < N_NODES) d.y = deg_off[base + 1];
        if (base + 2 < N_NODES) d.z = deg_off[base + 2];
    }
    int total = d.x + d.y + d.z + d.w;
    __shared__ int sc[256];
    sc[t] = total;
    __syncthreads();
    for (int off = 1; off < 256; off <<= 1) {
        int add = (t >= off) ? sc[t - off] : 0;
        __syncthreads();
        sc[t] += add;
        __syncthreads();
    }
    int texc = (t ? sc[t - 1] : 0) + bsum[blockIdx.x];
    int4 o;
    o.x = texc;
    o.y = o.x + d.x;
    o.z = o.y + d.y;
    o.w = o.z + d.z;
    if (full) {
        *reinterpret_cast<int4*>(&deg_off[base]) = o;
    } else {
        if (base + 0 < N_NODES) deg_off[base + 0] = o.x;
        if (base + 1 < N_NODES) deg_off[base + 1] = o.y;
        if (base + 2 < N_NODES) deg_off[base + 2] = o.z;
    }
}

// ---------------- two-pass multisplit partition into coarse buckets ----------------

// Pass A: per-block histogram of buckets.
__global__ __launch_bounds__(256) void k_phist(const int* __restrict__ dst,
                                               int* __restrict__ bhist) {
    __shared__ int cnt[NCB];
    int t = threadIdx.x;
    for (int i = t; i < NCB; i += 256) cnt[i] = 0;
    __syncthreads();
    int begin = blockIdx.x * EPB;
    int end = begin + EPB; if (end > N_EDGES) end = N_EDGES;
    for (int e = begin + t; e < end; e += 256)
        atomicAdd(&cnt[dst[e] >> CB_SHIFT], 1);
    __syncthreads();
    for (int i = t; i < NCB; i += 256) bhist[i * PB + blockIdx.x] = cnt[i];
}

// Pass B: per-bucket exclusive scan across blocks.
__global__ __launch_bounds__(PB) void k_pscan(int* __restrict__ bhist) {
    __shared__ int s[PB];
    int b = blockIdx.x, t = threadIdx.x;
    int v = bhist[b * PB + t];
    s[t] = v;
    __syncthreads();
    for (int off = 1; off < PB; off <<= 1) {
        int add = (t >= off) ? s[t - off] : 0;
        __syncthreads();
        s[t] += add;
        __syncthreads();
    }
    bhist[b * PB + t] = (t ? s[t - 1] : 0);
}

// Pass C: scatter edges to per-(bucket,block) private contiguous runs.
__global__ __launch_bounds__(256) void k_pscatter(const int* __restrict__ src,
                                                  const int* __restrict__ dst,
                                                  const int* __restrict__ bhist,
                                                  int* __restrict__ tmp) {
    __shared__ int cur[NCB];
    int t = threadIdx.x;
    for (int i = t; i < NCB; i += 256) cur[i] = bhist[i * PB + blockIdx.x];
    __syncthreads();
    int begin = blockIdx.x * EPB;
    int end = begin + EPB; if (end > N_EDGES) end = N_EDGES;
    for (int e = begin + t; e < end; e += 256) {
        int d = dst[e];
        int b = d >> CB_SHIFT;
        int pos = atomicAdd(&cur[b], 1);
        tmp[b * CB_CAP + pos] = ((d & (CB_NODES - 1)) << 17) | src[e];
    }
}

// ---------------- per-bucket scatter into CSR order (block-private region) ----------------

__global__ __launch_bounds__(256) void k_bsort(const int* __restrict__ tmp,
                                               const int* __restrict__ offs,
                                               int* __restrict__ ssrc) {
    __shared__ int lcur[CB_NODES];
    int b = blockIdx.x;
    int n0 = b << CB_SHIFT;
    int t = threadIdx.x;
    for (int j = t; j < CB_NODES; j += 256) {
        int n = n0 + j;
        lcur[j] = (n < N_NODES) ? offs[n] : 0;
    }
    __syncthreads();
    int startCsr = offs[n0];
    int endCsr = (n0 + CB_NODES >= N_NODES) ? N_EDGES : offs[n0 + CB_NODES];
    int cnt = endCsr - startCsr;
    const int* tp = &tmp[b * CB_CAP];
    for (int i = t; i < cnt; i += 256) {
        int p = tp[i];
        int pos = atomicAdd(&lcur[p >> 17], 1);
        ssrc[pos] = p & 0x1FFFF;
    }
}

// ---------------- x (f32) -> bf16 node table ----------------

__global__ __launch_bounds__(256) void k_cvt(const float* __restrict__ x,
                                             u16* __restrict__ hb) {
    int i = blockIdx.x * 256 + threadIdx.x;  // 8 elems each
    const int total = N_NODES * FEAT / 8;
    if (i < total) {
        const float4* xv = (const float4*)x;
        float4 a = xv[2 * i], b = xv[2 * i + 1];
        uint4 o;
        o.x = f2bf(a.x) | ((u32)f2bf(a.y) << 16);
        o.y = f2bf(a.z) | ((u32)f2bf(a.w) << 16);
        o.z = f2bf(b.x) | ((u32)f2bf(b.y) << 16);
        o.w = f2bf(b.z) | ((u32)f2bf(b.w) << 16);
        ((uint4*)hb)[i] = o;
    }
}

// ---------------- GIN aggregation: 2 nodes per wave, u32 (2 bf16) per lane ----------------

__global__ __launch_bounds__(256) void k_aggregate(const u16* __restrict__ hb,
                                                   float* __restrict__ agg,
                                                   const int* __restrict__ offs,
                                                   const int* __restrict__ ssrc) {
    int w = threadIdx.x >> 6;
    int lane = threadIdx.x & 63;
    int half = lane >> 5;
    int li = lane & 31;
    int node = blockIdx.x * 8 + w * 2 + half;
    if (node >= N_NODES) return;
    const u32* hb32 = (const u32*)hb;
    u32 pv = hb32[node * 32 + li];
    float v0 = bf2f((u16)(pv & 0xFFFF));
    float v1 = bf2f((u16)(pv >> 16));
    int s = offs[node];
    int e = (node + 1 < N_NODES) ? offs[node + 1] : N_EDGES;
    int j = s;
    for (; j + 3 < e; j += 4) {
        int s0 = ssrc[j], s1 = ssrc[j + 1], s2 = ssrc[j + 2], s3 = ssrc[j + 3];
        u32 n0 = hb32[s0 * 32 + li];
        u32 n1 = hb32[s1 * 32 + li];
        u32 n2 = hb32[s2 * 32 + li];
        u32 n3 = hb32[s3 * 32 + li];
        v0 += bf2f((u16)(n0 & 0xFFFF)); v1 += bf2f((u16)(n0 >> 16));
        v0 += bf2f((u16)(n1 & 0xFFFF)); v1 += bf2f((u16)(n1 >> 16));
        v0 += bf2f((u16)(n2 & 0xFFFF)); v1 += bf2f((u16)(n2 >> 16));
        v0 += bf2f((u16)(n3 & 0xFFFF)); v1 += bf2f((u16)(n3 >> 16));
    }
    for (; j < e; ++j) {
        u32 nv = hb32[ssrc[j] * 32 + li];
        v0 += bf2f((u16)(nv & 0xFFFF));
        v1 += bf2f((u16)(nv >> 16));
    }
    float2* outp = (float2*)(agg + (size_t)node * FEAT);
    outp[li] = make_float2(v0, v1);
}

// ---------------- fused 64->64->64 MLP (f32 math, bf16 output table) ----------------

template <bool RELU_OUT>
__global__ __launch_bounds__(256) void k_mlp(const float* __restrict__ agg,
                                             u16* __restrict__ hout,
                                             const float* __restrict__ W1,
                                             const float* __restrict__ b1,
                                             const float* __restrict__ W2,
                                             const float* __restrict__ b2) {
    __shared__ float w1s[FEAT * FEAT];
    __shared__ float w2s[FEAT * FEAT];
    __shared__ float b1s[FEAT];
    __shared__ float b2s[FEAT];
    {
        const float4* W1v = (const float4*)W1;
        const float4* W2v = (const float4*)W2;
        float4* w1sv = (float4*)w1s;
        float4* w2sv = (float4*)w2s;
        for (int i = threadIdx.x; i < FEAT * FEAT / 4; i += 256) {
            w1sv[i] = W1v[i];
            w2sv[i] = W2v[i];
        }
        if (threadIdx.x < FEAT) {
            b1s[threadIdx.x] = b1[threadIdx.x];
            b2s[threadIdx.x] = b2[threadIdx.x];
        }
    }
    __syncthreads();

    int node = blockIdx.x * 256 + threadIdx.x;
    if (node >= N_NODES) return;

    float a[FEAT], h[FEAT];
    const float4* av = (const float4*)(agg + (size_t)node * FEAT);
#pragma unroll
    for (int q = 0; q < FEAT / 4; ++q) {
        float4 v = av[q];
        a[4 * q + 0] = v.x; a[4 * q + 1] = v.y; a[4 * q + 2] = v.z; a[4 * q + 3] = v.w;
    }

    const float4* w1v = (const float4*)w1s;
    const float4* b1v = (const float4*)b1s;
#pragma unroll
    for (int q = 0; q < FEAT / 4; ++q) {
        float4 b = b1v[q];
        h[4 * q + 0] = b.x; h[4 * q + 1] = b.y; h[4 * q + 2] = b.z; h[4 * q + 3] = b.w;
    }
#pragma unroll
    for (int k = 0; k < FEAT; ++k) {
        float ak = a[k];
#pragma unroll
        for (int q = 0; q < FEAT / 4; ++q) {
            float4 w = w1v[k * (FEAT / 4) + q];
            h[4 * q + 0] = fmaf(ak, w.x, h[4 * q + 0]);
            h[4 * q + 1] = fmaf(ak, w.y, h[4 * q + 1]);
            h[4 * q + 2] = fmaf(ak, w.z, h[4 * q + 2]);
            h[4 * q + 3] = fmaf(ak, w.w, h[4 * q + 3]);
        }
    }
#pragma unroll
    for (int j = 0; j < FEAT; ++j) h[j] = fmaxf(h[j], 0.0f);

    const float4* w2v = (const float4*)w2s;
    const float4* b2v = (const float4*)b2s;
#pragma unroll
    for (int q = 0; q < FEAT / 4; ++q) {
        float4 b = b2v[q];
        a[4 * q + 0] = b.x; a[4 * q + 1] = b.y; a[4 * q + 2] = b.z; a[4 * q + 3] = b.w;
    }
#pragma unroll
    for (int k = 0; k < FEAT; ++k) {
        float hk = h[k];
#pragma unroll
        for (int q = 0; q < FEAT / 4; ++q) {
            float4 w = w2v[k * (FEAT / 4) + q];
            a[4 * q + 0] = fmaf(hk, w.x, a[4 * q + 0]);
            a[4 * q + 1] = fmaf(hk, w.y, a[4 * q + 1]);
            a[4 * q + 2] = fmaf(hk, w.z, a[4 * q + 2]);
            a[4 * q + 3] = fmaf(hk, w.w, a[4 * q + 3]);
        }
    }
    if (RELU_OUT) {
#pragma unroll
        for (int j = 0; j < FEAT; ++j) a[j] = fmaxf(a[j], 0.0f);
    }

    u32 w[FEAT / 2];
#pragma unroll
    for (int q = 0; q < FEAT / 2; ++q)
        w[q] = f2bf(a[2 * q]) | ((u32)f2bf(a[2 * q + 1]) << 16);
    uint4* ov = (uint4*)(hout + (size_t)node * FEAT);
#pragma unroll
    for (int q = 0; q < FEAT / 8; ++q)
        ov[q] = make_uint4(w[4 * q + 0], w[4 * q + 1], w[4 * q + 2], w[4 * q + 3]);
}

// ---------------- last layer: fused aggregate + (64->1->1) -> scalar per node ----------------

__global__ __launch_bounds__(256) void k_lastagg(const u16* __restrict__ hb,
                                                 const int* __restrict__ offs,
                                                 const int* __restrict__ ssrc,
                                                 const float* __restrict__ W1l,
                                                 const float* __restrict__ b1l,
                                                 const float* __restrict__ W2l,
                                                 const float* __restrict__ b2l,
                                                 float* __restrict__ o) {
    int w = threadIdx.x >> 6;
    int lane = threadIdx.x & 63;
    int half = lane >> 5;
    int li = lane & 31;
    int node = blockIdx.x * 8 + w * 2 + half;
    if (node >= N_NODES) return;
    const u32* hb32 = (const u32*)hb;
    u32 pv = hb32[node * 32 + li];
    float v0 = bf2f((u16)(pv & 0xFFFF));
    float v1 = bf2f((u16)(pv >> 16));
    int s = offs[node];
    int e = (node + 1 < N_NODES) ? offs[node + 1] : N_EDGES;
    int j = s;
    for (; j + 1 < e; j += 2) {
        u32 n0 = hb32[ssrc[j] * 32 + li];
        u32 n1 = hb32[ssrc[j + 1] * 32 + li];
        v0 += bf2f((u16)(n0 & 0xFFFF)); v1 += bf2f((u16)(n0 >> 16));
        v0 += bf2f((u16)(n1 & 0xFFFF)); v1 += bf2f((u16)(n1 >> 16));
    }
    if (j < e) {
        u32 nv = hb32[ssrc[j] * 32 + li];
        v0 += bf2f((u16)(nv & 0xFFFF));
        v1 += bf2f((u16)(nv >> 16));
    }
    float v = v0 * W1l[2 * li] + v1 * W1l[2 * li + 1];
#pragma unroll
    for (int off = 16; off; off >>= 1) v += __shfl_xor(v, off);  // within 32-lane half
    if (li == 0) {
        float h1 = fmaxf(v + b1l[0], 0.0f);
        o[node] = fmaf(h1, W2l[0], b2l[0]);
    }
}

// ---------------- mean pool ----------------

__global__ __launch_bounds__(256) void k_pool(const float* __restrict__ o,
                                              const int* __restrict__ batch,
                                              float* __restrict__ out) {
    int g = blockIdx.x;
    int lo = 0, hi = N_NODES;
    while (lo < hi) { int mid = (lo + hi) >> 1; if (batch[mid] < g) lo = mid + 1; else hi = mid; }
    int start = lo;
    hi = N_NODES;
    while (lo < hi) { int mid = (lo + hi) >> 1; if (batch[mid] < g + 1) lo = mid + 1; else hi = mid; }
    int end = lo;

    float s = 0.0f;
    for (int i = start + threadIdx.x; i < end; i += 256) s += o[i];
#pragma unroll
    for (int off = 32; off; off >>= 1) s += __shfl_xor(s, off);
    __shared__ float red[4];
    int lane = threadIdx.x & 63, wid = threadIdx.x >> 6;
    if (lane == 0) red[wid] = s;
    __syncthreads();
    if (threadIdx.x == 0) {
        float t = red[0] + red[1] + red[2] + red[3];
        float c = (float)(end - start);
        out[g] = t / fmaxf(c, 1.0f);
    }
}

// ---------------- launch ----------------

extern "C" void kernel_launch(void* const* d_in, const int* in_sizes, int n_in,
                              void* d_out, int out_size, void* d_ws, size_t ws_size,
                              hipStream_t stream) {
    const float* x    = (const float*)d_in[0];
    const int*   ei   = (const int*)d_in[1];   // [2][N_EDGES]
    const int*   bat  = (const int*)d_in[2];
    const float* W1   = (const float*)d_in[3];
    const float* b1   = (const float*)d_in[4];
    const float* W2   = (const float*)d_in[5];
    const float* b2   = (const float*)d_in[6];
    const float* W1l  = (const float*)d_in[7];
    const float* b1l  = (const float*)d_in[8];
    const float* W2l  = (const float*)d_in[9];
    const float* b2l  = (const float*)d_in[10];
    float* out = (float*)d_out;

    const int* srcI = ei;            // row 0
    const int* dstI = ei + N_EDGES;  // row 1

    // workspace carve-up (all 16B-aligned)
    char* ws = (char*)d_ws;
    float* agg   = (float*)ws;                              ws += (size_t)N_NODES * FEAT * 4;
    u16*   hb    = (u16*)ws;                                ws += (size_t)N_NODES * FEAT * 2;
    int*   offs  = (int*)ws;                                ws += (size_t)N_NODES * 4;
    int*   ssrc  = (int*)ws;                                ws += (size_t)N_EDGES * 4;
    int*   tmp   = (int*)ws;                                ws += (size_t)NCB * CB_CAP * 4;
    float* onode = (float*)ws;                              ws += (size_t)N_NODES * 4;
    int*   bsum  = (int*)ws;                                ws += 128 * 4;
    int*   bhist = (int*)ws;                                ws += (size_t)NCB * PB * 4;

    hipMemsetAsync(offs, 0, (size_t)N_NODES * 4, stream);

    const int EB = 256;
    const int egrid = (N_EDGES + EB - 1) / EB;
    k_hist<<<egrid, EB, 0, stream>>>(dstI, offs);
    k_scan1<<<SCAN_BLOCKS, 256, 0, stream>>>(offs, bsum);
    k_scan2<<<1, 128, 0, stream>>>(bsum);
    k_scan3<<<SCAN_BLOCKS, 256, 0, stream>>>(offs, bsum);
    k_phist<<<PB, 256, 0, stream>>>(dstI, bhist);
    k_pscan<<<NCB, PB, 0, stream>>>(bhist);
    k_pscatter<<<PB, 256, 0, stream>>>(srcI, dstI, bhist, tmp);
    k_bsort<<<NCB, 256, 0, stream>>>(tmp, offs, ssrc);
    k_cvt<<<(N_NODES * FEAT / 8 + 255) / 256, 256, 0, stream>>>(x, hb);

    const int ngrid = (N_NODES + 7) / 8;      // aggregate: 8 nodes (2 per wave) per block
    const int mgrid = (N_NODES + 255) / 256;  // mlp: thread per node

    for (int l = 0; l < 4; ++l) {
        k_aggregate<<<ngrid, 256, 0, stream>>>(hb, agg, offs, ssrc);
        k_mlp<true><<<mgrid, 256, 0, stream>>>(agg, hb,
                                               W1 + (size_t)l * FEAT * FEAT,
                                               b1 + (size_t)l * FEAT,
                                               W2 + (size_t)l * FEAT * FEAT,
                                               b2 + (size_t)l * FEAT);
    }
    k_lastagg<<<ngrid, 256, 0, stream>>>(hb, offs, ssrc, W1l, b1l, W2l, b2l, onode);
    k_pool<<<NGRAPH, 256, 0, stream>>>(onode, bat, out);
}

// Round 8
// 474.288 us; speedup vs baseline: 3.9457x; 1.1214x over previous
//
#include <hip/hip_runtime.h>
#include <hip/hip_bf16.h>

#define N_NODES 100000
#define N_EDGES 1600000
#define FEAT 64
#define NGRAPH 256

#define SCAN_CHUNK 1024
#define SCAN_BLOCKS ((N_NODES + SCAN_CHUNK - 1) / SCAN_CHUNK)  // 98

// coarse buckets: 1024 nodes each
#define CB_SHIFT 10
#define CB_NODES 1024
#define NCB ((N_NODES + CB_NODES - 1) / CB_NODES)   // 98
#define CB_CAP 18432                                 // slots per bucket (mean 16384, +16 sigma)

#define PB 512                                       // partition blocks
#define EPB ((N_EDGES + PB - 1) / PB)                // 3125 edges per block

typedef unsigned short u16;
typedef unsigned int u32;

static __device__ __forceinline__ float bf2f(u16 h) {
    return __uint_as_float(((u32)h) << 16);
}
static __device__ __forceinline__ u16 f2bf(float x) {  // round-to-nearest-even (finite)
    u32 u = __float_as_uint(x);
    return (u16)((u + 0x7FFF + ((u >> 16) & 1)) >> 16);
}

// ---------------- two-pass multisplit partition into coarse buckets ----------------

// Pass A: per-block histogram of buckets.
__global__ __launch_bounds__(256) void k_phist(const int* __restrict__ dst,
                                               int* __restrict__ bhist) {
    __shared__ int cnt[NCB];
    int t = threadIdx.x;
    for (int i = t; i < NCB; i += 256) cnt[i] = 0;
    __syncthreads();
    int begin = blockIdx.x * EPB;
    int end = begin + EPB; if (end > N_EDGES) end = N_EDGES;
    for (int e = begin + t; e < end; e += 256)
        atomicAdd(&cnt[dst[e] >> CB_SHIFT], 1);
    __syncthreads();
    for (int i = t; i < NCB; i += 256) bhist[i * PB + blockIdx.x] = cnt[i];
}

// Pass B: per-bucket exclusive scan across blocks; also emit bucket totals.
__global__ __launch_bounds__(PB) void k_pscan(int* __restrict__ bhist,
                                              int* __restrict__ gtot) {
    __shared__ int s[PB];
    int b = blockIdx.x, t = threadIdx.x;
    int v = bhist[b * PB + t];
    s[t] = v;
    __syncthreads();
    for (int off = 1; off < PB; off <<= 1) {
        int add = (t >= off) ? s[t - off] : 0;
        __syncthreads();
        s[t] += add;
        __syncthreads();
    }
    int incl = s[t];
    bhist[b * PB + t] = (t ? s[t - 1] : 0);
    if (t == PB - 1) gtot[b] = incl;
}

// Pass C: scatter edges to per-(bucket,block) private contiguous runs.
__global__ __launch_bounds__(256) void k_pscatter(const int* __restrict__ src,
                                                  const int* __restrict__ dst,
                                                  const int* __restrict__ bhist,
                                                  int* __restrict__ tmp) {
    __shared__ int cur[NCB];
    int t = threadIdx.x;
    for (int i = t; i < NCB; i += 256) cur[i] = bhist[i * PB + blockIdx.x];
    __syncthreads();
    int begin = blockIdx.x * EPB;
    int end = begin + EPB; if (end > N_EDGES) end = N_EDGES;
    for (int e = begin + t; e < end; e += 256) {
        int d = dst[e];
        int b = d >> CB_SHIFT;
        int pos = atomicAdd(&cur[b], 1);
        if (pos < CB_CAP) tmp[b * CB_CAP + pos] = ((d & (CB_NODES - 1)) << 17) | src[e];
    }
}

// ---------------- per-bucket degree count (LDS histogram, coalesced write) ----------------

__global__ __launch_bounds__(256) void k_bdeg(const int* __restrict__ tmp,
                                              const int* __restrict__ gtot,
                                              int* __restrict__ deg) {
    __shared__ int cnt[CB_NODES];
    int b = blockIdx.x, t = threadIdx.x;
    for (int j = t; j < CB_NODES; j += 256) cnt[j] = 0;
    __syncthreads();
    int n = gtot[b]; if (n > CB_CAP) n = CB_CAP;
    const int* tp = &tmp[b * CB_CAP];
    for (int i = t; i < n; i += 256) atomicAdd(&cnt[tp[i] >> 17], 1);
    __syncthreads();
    int n0 = b << CB_SHIFT;
    for (int j = t; j < CB_NODES; j += 256) {
        int node = n0 + j;
        if (node < N_NODES) deg[node] = cnt[j];
    }
}

// ---------------- CSR offset scan (deg -> offs, in place) ----------------

__global__ __launch_bounds__(256) void k_scan1(const int* __restrict__ deg,
                                               int* __restrict__ bsum) {
    int t = threadIdx.x;
    int base = blockIdx.x * SCAN_CHUNK + t * 4;
    int4 d = make_int4(0, 0, 0, 0);
    if (base + 3 < N_NODES) {
        d = *reinterpret_cast<const int4*>(&deg[base]);
    } else {
        if (base + 0 < N_NODES) d.x = deg[base + 0];
        if (base + 1 < N_NODES) d.y = deg[base + 1];
        if (base + 2 < N_NODES) d.z = deg[base + 2];
    }
    int v = d.x + d.y + d.z + d.w;
#pragma unroll
    for (int off = 32; off; off >>= 1) v += __shfl_xor(v, off);
    __shared__ int red[4];
    int lane = t & 63, wid = t >> 6;
    if (lane == 0) red[wid] = v;
    __syncthreads();
    if (t == 0) bsum[blockIdx.x] = red[0] + red[1] + red[2] + red[3];
}

__global__ __launch_bounds__(128) void k_scan2(int* __restrict__ bsum) {
    __shared__ int s[128];
    int t = threadIdx.x;
    int v = (t < SCAN_BLOCKS) ? bsum[t] : 0;
    s[t] = v;
    __syncthreads();
    for (int off = 1; off < 128; off <<= 1) {
        int add = (t >= off) ? s[t - off] : 0;
        __syncthreads();
        s[t] += add;
        __syncthreads();
    }
    if (t < SCAN_BLOCKS) bsum[t] = (t ? s[t - 1] : 0);
}

__global__ __launch_bounds__(256) void k_scan3(int* __restrict__ deg_off,
                                               const int* __restrict__ bsum) {
    int t = threadIdx.x;
    int base = blockIdx.x * SCAN_CHUNK + t * 4;
    int4 d = make_int4(0, 0, 0, 0);
    bool full = (base + 3 < N_NODES);
    if (full) {
        d = *reinterpret_cast<const int4*>(&deg_off[base]);
    } else {
        if (base + 0 < N_NODES) d.x = deg_off[base + 0];
        if (base + 1 < N_NODES) d.y = deg_off[base + 1];
        if (base + 2 < N_NODES) d.z = deg_off[base + 2];
    }
    int total = d.x + d.y + d.z + d.w;
    __shared__ int sc[256];
    sc[t] = total;
    __syncthreads();
    for (int off = 1; off < 256; off <<= 1) {
        int add = (t >= off) ? sc[t - off] : 0;
        __syncthreads();
        sc[t] += add;
        __syncthreads();
    }
    int texc = (t ? sc[t - 1] : 0) + bsum[blockIdx.x];
    int4 o;
    o.x = texc;
    o.y = o.x + d.x;
    o.z = o.y + d.y;
    o.w = o.z + d.z;
    if (full) {
        *reinterpret_cast<int4*>(&deg_off[base]) = o;
    } else {
        if (base + 0 < N_NODES) deg_off[base + 0] = o.x;
        if (base + 1 < N_NODES) deg_off[base + 1] = o.y;
        if (base + 2 < N_NODES) deg_off[base + 2] = o.z;
    }
}

// ---------------- per-bucket scatter into CSR order (block-private region) ----------------

__global__ __launch_bounds__(256) void k_bsort(const int* __restrict__ tmp,
                                               const int* __restrict__ offs,
                                               const int* __restrict__ gtot,
                                               int* __restrict__ ssrc) {
    __shared__ int lcur[CB_NODES];
    int b = blockIdx.x;
    int n0 = b << CB_SHIFT;
    int t = threadIdx.x;
    for (int j = t; j < CB_NODES; j += 256) {
        int n = n0 + j;
        lcur[j] = (n < N_NODES) ? offs[n] : 0;
    }
    __syncthreads();
    int cnt = gtot[b]; if (cnt > CB_CAP) cnt = CB_CAP;
    const int* tp = &tmp[b * CB_CAP];
    for (int i = t; i < cnt; i += 256) {
        int p = tp[i];
        int pos = atomicAdd(&lcur[p >> 17], 1);
        ssrc[pos] = p & 0x1FFFF;
    }
}

// ---------------- x (f32) -> bf16 node table ----------------

__global__ __launch_bounds__(256) void k_cvt(const float* __restrict__ x,
                                             u16* __restrict__ hb) {
    int i = blockIdx.x * 256 + threadIdx.x;  // 8 elems each
    const int total = N_NODES * FEAT / 8;
    if (i < total) {
        const float4* xv = (const float4*)x;
        float4 a = xv[2 * i], b = xv[2 * i + 1];
        uint4 o;
        o.x = f2bf(a.x) | ((u32)f2bf(a.y) << 16);
        o.y = f2bf(a.z) | ((u32)f2bf(a.w) << 16);
        o.z = f2bf(b.x) | ((u32)f2bf(b.y) << 16);
        o.w = f2bf(b.z) | ((u32)f2bf(b.w) << 16);
        ((uint4*)hb)[i] = o;
    }
}

// ---------------- GIN aggregation: 2 nodes per wave, u32 (2 bf16) per lane ----------------

__global__ __launch_bounds__(256) void k_aggregate(const u16* __restrict__ hb,
                                                   float* __restrict__ agg,
                                                   const int* __restrict__ offs,
                                                   const int* __restrict__ ssrc) {
    int w = threadIdx.x >> 6;
    int lane = threadIdx.x & 63;
    int half = lane >> 5;
    int li = lane & 31;
    int node = blockIdx.x * 8 + w * 2 + half;
    if (node >= N_NODES) return;
    const u32* hb32 = (const u32*)hb;
    u32 pv = hb32[node * 32 + li];
    float v0 = bf2f((u16)(pv & 0xFFFF));
    float v1 = bf2f((u16)(pv >> 16));
    int s = offs[node];
    int e = (node + 1 < N_NODES) ? offs[node + 1] : N_EDGES;
    int j = s;
    for (; j + 3 < e; j += 4) {
        int s0 = ssrc[j], s1 = ssrc[j + 1], s2 = ssrc[j + 2], s3 = ssrc[j + 3];
        u32 n0 = hb32[s0 * 32 + li];
        u32 n1 = hb32[s1 * 32 + li];
        u32 n2 = hb32[s2 * 32 + li];
        u32 n3 = hb32[s3 * 32 + li];
        v0 += bf2f((u16)(n0 & 0xFFFF)); v1 += bf2f((u16)(n0 >> 16));
        v0 += bf2f((u16)(n1 & 0xFFFF)); v1 += bf2f((u16)(n1 >> 16));
        v0 += bf2f((u16)(n2 & 0xFFFF)); v1 += bf2f((u16)(n2 >> 16));
        v0 += bf2f((u16)(n3 & 0xFFFF)); v1 += bf2f((u16)(n3 >> 16));
    }
    for (; j < e; ++j) {
        u32 nv = hb32[ssrc[j] * 32 + li];
        v0 += bf2f((u16)(nv & 0xFFFF));
        v1 += bf2f((u16)(nv >> 16));
    }
    float2* outp = (float2*)(agg + (size_t)node * FEAT);
    outp[li] = make_float2(v0, v1);
}

// ---------------- fused 64->64->64 MLP (f32 math, bf16 output table) ----------------

template <bool RELU_OUT>
__global__ __launch_bounds__(256) void k_mlp(const float* __restrict__ agg,
                                             u16* __restrict__ hout,
                                             const float* __restrict__ W1,
                                             const float* __restrict__ b1,
                                             const float* __restrict__ W2,
                                             const float* __restrict__ b2) {
    __shared__ float w1s[FEAT * FEAT];
    __shared__ float w2s[FEAT * FEAT];
    __shared__ float b1s[FEAT];
    __shared__ float b2s[FEAT];
    {
        const float4* W1v = (const float4*)W1;
        const float4* W2v = (const float4*)W2;
        float4* w1sv = (float4*)w1s;
        float4* w2sv = (float4*)w2s;
        for (int i = threadIdx.x; i < FEAT * FEAT / 4; i += 256) {
            w1sv[i] = W1v[i];
            w2sv[i] = W2v[i];
        }
        if (threadIdx.x < FEAT) {
            b1s[threadIdx.x] = b1[threadIdx.x];
            b2s[threadIdx.x] = b2[threadIdx.x];
        }
    }
    __syncthreads();

    int node = blockIdx.x * 256 + threadIdx.x;
    if (node >= N_NODES) return;

    float a[FEAT], h[FEAT];
    const float4* av = (const float4*)(agg + (size_t)node * FEAT);
#pragma unroll
    for (int q = 0; q < FEAT / 4; ++q) {
        float4 v = av[q];
        a[4 * q + 0] = v.x; a[4 * q + 1] = v.y; a[4 * q + 2] = v.z; a[4 * q + 3] = v.w;
    }

    const float4* w1v = (const float4*)w1s;
    const float4* b1v = (const float4*)b1s;
#pragma unroll
    for (int q = 0; q < FEAT / 4; ++q) {
        float4 b = b1v[q];
        h[4 * q + 0] = b.x; h[4 * q + 1] = b.y; h[4 * q + 2] = b.z; h[4 * q + 3] = b.w;
    }
#pragma unroll
    for (int k = 0; k < FEAT; ++k) {
        float ak = a[k];
#pragma unroll
        for (int q = 0; q < FEAT / 4; ++q) {
            float4 w = w1v[k * (FEAT / 4) + q];
            h[4 * q + 0] = fmaf(ak, w.x, h[4 * q + 0]);
            h[4 * q + 1] = fmaf(ak, w.y, h[4 * q + 1]);
            h[4 * q + 2] = fmaf(ak, w.z, h[4 * q + 2]);
            h[4 * q + 3] = fmaf(ak, w.w, h[4 * q + 3]);
        }
    }
#pragma unroll
    for (int j = 0; j < FEAT; ++j) h[j] = fmaxf(h[j], 0.0f);

    const float4* w2v = (const float4*)w2s;
    const float4* b2v = (const float4*)b2s;
#pragma unroll
    for (int q = 0; q < FEAT / 4; ++q) {
        float4 b = b2v[q];
        a[4 * q + 0] = b.x; a[4 * q + 1] = b.y; a[4 * q + 2] = b.z; a[4 * q + 3] = b.w;
    }
#pragma unroll
    for (int k = 0; k < FEAT; ++k) {
        float hk = h[k];
#pragma unroll
        for (int q = 0; q < FEAT / 4; ++q) {
            float4 w = w2v[k * (FEAT / 4) + q];
            a[4 * q + 0] = fmaf(hk, w.x, a[4 * q + 0]);
            a[4 * q + 1] = fmaf(hk, w.y, a[4 * q + 1]);
            a[4 * q + 2] = fmaf(hk, w.z, a[4 * q + 2]);
            a[4 * q + 3] = fmaf(hk, w.w, a[4 * q + 3]);
        }
    }
    if (RELU_OUT) {
#pragma unroll
        for (int j = 0; j < FEAT; ++j) a[j] = fmaxf(a[j], 0.0f);
    }

    u32 w[FEAT / 2];
#pragma unroll
    for (int q = 0; q < FEAT / 2; ++q)
        w[q] = f2bf(a[2 * q]) | ((u32)f2bf(a[2 * q + 1]) << 16);
    uint4* ov = (uint4*)(hout + (size_t)node * FEAT);
#pragma unroll
    for (int q = 0; q < FEAT / 8; ++q)
        ov[q] = make_uint4(w[4 * q + 0], w[4 * q + 1], w[4 * q + 2], w[4 * q + 3]);
}

// ---------------- last layer: fused aggregate + (64->1->1) -> scalar per node ----------------

__global__ __launch_bounds__(256) void k_lastagg(const u16* __restrict__ hb,
                                                 const int* __restrict__ offs,
                                                 const int* __restrict__ ssrc,
                                                 const float* __restrict__ W1l,
                                                 const float* __restrict__ b1l,
                                                 const float* __restrict__ W2l,
                                                 const float* __restrict__ b2l,
                                                 float* __restrict__ o) {
    int w = threadIdx.x >> 6;
    int lane = threadIdx.x & 63;
    int half = lane >> 5;
    int li = lane & 31;
    int node = blockIdx.x * 8 + w * 2 + half;
    if (node >= N_NODES) return;
    const u32* hb32 = (const u32*)hb;
    u32 pv = hb32[node * 32 + li];
    float v0 = bf2f((u16)(pv & 0xFFFF));
    float v1 = bf2f((u16)(pv >> 16));
    int s = offs[node];
    int e = (node + 1 < N_NODES) ? offs[node + 1] : N_EDGES;
    int j = s;
    for (; j + 1 < e; j += 2) {
        u32 n0 = hb32[ssrc[j] * 32 + li];
        u32 n1 = hb32[ssrc[j + 1] * 32 + li];
        v0 += bf2f((u16)(n0 & 0xFFFF)); v1 += bf2f((u16)(n0 >> 16));
        v0 += bf2f((u16)(n1 & 0xFFFF)); v1 += bf2f((u16)(n1 >> 16));
    }
    if (j < e) {
        u32 nv = hb32[ssrc[j] * 32 + li];
        v0 += bf2f((u16)(nv & 0xFFFF));
        v1 += bf2f((u16)(nv >> 16));
    }
    float v = v0 * W1l[2 * li] + v1 * W1l[2 * li + 1];
#pragma unroll
    for (int off = 16; off; off >>= 1) v += __shfl_xor(v, off);  // within 32-lane half
    if (li == 0) {
        float h1 = fmaxf(v + b1l[0], 0.0f);
        o[node] = fmaf(h1, W2l[0], b2l[0]);
    }
}

// ---------------- mean pool ----------------

__global__ __launch_bounds__(256) void k_pool(const float* __restrict__ o,
                                              const int* __restrict__ batch,
                                              float* __restrict__ out) {
    int g = blockIdx.x;
    int lo = 0, hi = N_NODES;
    while (lo < hi) { int mid = (lo + hi) >> 1; if (batch[mid] < g) lo = mid + 1; else hi = mid; }
    int start = lo;
    hi = N_NODES;
    while (lo < hi) { int mid = (lo + hi) >> 1; if (batch[mid] < g + 1) lo = mid + 1; else hi = mid; }
    int end = lo;

    float s = 0.0f;
    for (int i = start + threadIdx.x; i < end; i += 256) s += o[i];
#pragma unroll
    for (int off = 32; off; off >>= 1) s += __shfl_xor(s, off);
    __shared__ float red[4];
    int lane = threadIdx.x & 63, wid = threadIdx.x >> 6;
    if (lane == 0) red[wid] = s;
    __syncthreads();
    if (threadIdx.x == 0) {
        float t = red[0] + red[1] + red[2] + red[3];
        float c = (float)(end - start);
        out[g] = t / fmaxf(c, 1.0f);
    }
}

// ---------------- launch ----------------

extern "C" void kernel_launch(void* const* d_in, const int* in_sizes, int n_in,
                              void* d_out, int out_size, void* d_ws, size_t ws_size,
                              hipStream_t stream) {
    const float* x    = (const float*)d_in[0];
    const int*   ei   = (const int*)d_in[1];   // [2][N_EDGES]
    const int*   bat  = (const int*)d_in[2];
    const float* W1   = (const float*)d_in[3];
    const float* b1   = (const float*)d_in[4];
    const float* W2   = (const float*)d_in[5];
    const float* b2   = (const float*)d_in[6];
    const float* W1l  = (const float*)d_in[7];
    const float* b1l  = (const float*)d_in[8];
    const float* W2l  = (const float*)d_in[9];
    const float* b2l  = (const float*)d_in[10];
    float* out = (float*)d_out;

    const int* srcI = ei;            // row 0
    const int* dstI = ei + N_EDGES;  // row 1

    // workspace carve-up (all 16B-aligned)
    char* ws = (char*)d_ws;
    float* agg   = (float*)ws;                              ws += (size_t)N_NODES * FEAT * 4;
    u16*   hb    = (u16*)ws;                                ws += (size_t)N_NODES * FEAT * 2;
    int*   offs  = (int*)ws;                                ws += (size_t)N_NODES * 4;
    int*   ssrc  = (int*)ws;                                ws += (size_t)N_EDGES * 4;
    int*   tmp   = (int*)ws;                                ws += (size_t)NCB * CB_CAP * 4;
    float* onode = (float*)ws;                              ws += (size_t)N_NODES * 4;
    int*   bsum  = (int*)ws;                                ws += 128 * 4;
    int*   bhist = (int*)ws;                                ws += (size_t)NCB * PB * 4;
    int*   gtot  = (int*)ws;                                ws += ((NCB + 3) & ~3) * 4;

    // partition edges by coarse bucket (needs only dst), then derive degrees in LDS
    k_phist<<<PB, 256, 0, stream>>>(dstI, bhist);
    k_pscan<<<NCB, PB, 0, stream>>>(bhist, gtot);
    k_pscatter<<<PB, 256, 0, stream>>>(srcI, dstI, bhist, tmp);
    k_bdeg<<<NCB, 256, 0, stream>>>(tmp, gtot, offs);
    k_scan1<<<SCAN_BLOCKS, 256, 0, stream>>>(offs, bsum);
    k_scan2<<<1, 128, 0, stream>>>(bsum);
    k_scan3<<<SCAN_BLOCKS, 256, 0, stream>>>(offs, bsum);
    k_bsort<<<NCB, 256, 0, stream>>>(tmp, offs, gtot, ssrc);
    k_cvt<<<(N_NODES * FEAT / 8 + 255) / 256, 256, 0, stream>>>(x, hb);

    const int ngrid = (N_NODES + 7) / 8;      // aggregate: 8 nodes (2 per wave) per block
    const int mgrid = (N_NODES + 255) / 256;  // mlp: thread per node

    for (int l = 0; l < 4; ++l) {
        k_aggregate<<<ngrid, 256, 0, stream>>>(hb, agg, offs, ssrc);
        k_mlp<true><<<mgrid, 256, 0, stream>>>(agg, hb,
                                               W1 + (size_t)l * FEAT * FEAT,
                                               b1 + (size_t)l * FEAT,
                                               W2 + (size_t)l * FEAT * FEAT,
                                               b2 + (size_t)l * FEAT);
    }
    k_lastagg<<<ngrid, 256, 0, stream>>>(hb, offs, ssrc, W1l, b1l, W2l, b2l, onode);
    k_pool<<<NGRAPH, 256, 0, stream>>>(onode, bat, out);
}